// Round 9
// baseline (284.722 us; speedup 1.0000x reference)
//
#include <hip/hip_runtime.h>
#include <hip/hip_fp16.h>

#ifndef F1
#define F1 64
#define F2 32
#endif

#define NBLK 512     // blocks for bucket hist/scatter passes
#define BSH  7       // bucket = dst >> 7  (128 nodes per bucket)
#define BNODES 128

typedef _Float16 half8 __attribute__((ext_vector_type(8)));
typedef float floatx4 __attribute__((ext_vector_type(4)));

// ---------------- scans ----------------
__global__ __launch_bounds__(256) void scan_blocks_kernel(const int* __restrict__ in,
                                                          int* __restrict__ tmp,
                                                          int* __restrict__ blk_sums, int n) {
    __shared__ int sdata[256];
    int t = threadIdx.x;
    int base = blockIdx.x * 1024 + t * 4;
    int v[4];
#pragma unroll
    for (int j = 0; j < 4; ++j) v[j] = (base + j < n) ? in[base + j] : 0;
    int mysum = v[0] + v[1] + v[2] + v[3];
    sdata[t] = mysum;
    __syncthreads();
    for (int ofs = 1; ofs < 256; ofs <<= 1) {
        int val = (t >= ofs) ? sdata[t - ofs] : 0;
        __syncthreads();
        sdata[t] += val;
        __syncthreads();
    }
    int incl = sdata[t];
    int excl = incl - mysum;
    if (t == 255) blk_sums[blockIdx.x] = incl;
    int run = excl;
#pragma unroll
    for (int j = 0; j < 4; ++j) {
        if (base + j < n) tmp[base + j] = run;
        run += v[j];
    }
}

__global__ __launch_bounds__(512) void scan_sums_kernel(const int* __restrict__ blk_sums,
                                                        int* __restrict__ blk_scanned, int nb) {
    __shared__ int sdata[512];
    int t = threadIdx.x;
    int mine = (t < nb) ? blk_sums[t] : 0;
    sdata[t] = mine;
    __syncthreads();
    for (int ofs = 1; ofs < 512; ofs <<= 1) {
        int val = (t >= ofs) ? sdata[t - ofs] : 0;
        __syncthreads();
        sdata[t] += val;
        __syncthreads();
    }
    blk_scanned[t] = sdata[t] - mine;  // exclusive
}

// ---------------- bucket passes (counting sort by dst>>BSH) ----------------
// Block NBLK additionally does weight prep (fused to save a dispatch).

__global__ __launch_bounds__(256) void bucket_hist_prep_kernel(const int* __restrict__ dst,
                                                               int* __restrict__ hist_T,
                                                               const float* __restrict__ W1,
                                                               const float* __restrict__ W2,
                                                               __half* __restrict__ W1t,
                                                               __half* __restrict__ W2t,
                                                               int E, int CH, int NB) {
    int b = blockIdx.x;
    if (b == NBLK) {  // weight prep: Wt[n][k] = half(W[k][n])
        for (int e = threadIdx.x; e < 64 * 256; e += 256) {
            int n = e >> 8, k = e & 255;
            W1t[e] = __float2half(W1[k * 64 + n]);
        }
        for (int e = threadIdx.x; e < 32 * 64; e += 256) {
            int n = e >> 6, k = e & 63;
            W2t[e] = __float2half(W2[k * 32 + n]);
        }
        return;
    }
    __shared__ int lh[1024];
    for (int i = threadIdx.x; i < NB; i += 256) lh[i] = 0;
    __syncthreads();
    int start = b * CH, end = min(E, start + CH);
    for (int e0 = start + threadIdx.x * 4; e0 < end; e0 += 1024) {
        if (e0 + 4 <= end) {
            int4 d4 = *reinterpret_cast<const int4*>(dst + e0);
            atomicAdd(&lh[d4.x >> BSH], 1);
            atomicAdd(&lh[d4.y >> BSH], 1);
            atomicAdd(&lh[d4.z >> BSH], 1);
            atomicAdd(&lh[d4.w >> BSH], 1);
        } else {
            for (int e = e0; e < end; ++e) atomicAdd(&lh[dst[e] >> BSH], 1);
        }
    }
    __syncthreads();
    for (int k = threadIdx.x; k < NB; k += 256)
        hist_T[k * NBLK + b] = lh[k];
}

// Scatter packed (src<<7)|(dst&127) into contiguous bucket regions.
__global__ __launch_bounds__(256) void bucket_scatter_kernel(const int* __restrict__ src,
                                                             const int* __restrict__ dst,
                                                             const int* __restrict__ tmp,
                                                             const int* __restrict__ bscan,
                                                             int* __restrict__ buck,
                                                             int E, int CH, int NB) {
    __shared__ int cur[1024];
    int b = blockIdx.x;
    for (int i = threadIdx.x; i < NB; i += 256) {
        int idx = i * NBLK + b;
        cur[i] = tmp[idx] + bscan[idx >> 10];
    }
    __syncthreads();
    int start = b * CH, end = min(E, start + CH);
    for (int e0 = start + threadIdx.x * 4; e0 < end; e0 += 1024) {
        if (e0 + 4 <= end) {
            int4 s4 = *reinterpret_cast<const int4*>(src + e0);
            int4 d4 = *reinterpret_cast<const int4*>(dst + e0);
            int p0 = atomicAdd(&cur[d4.x >> BSH], 1);
            buck[p0] = (s4.x << BSH) | (d4.x & (BNODES - 1));
            int p1 = atomicAdd(&cur[d4.y >> BSH], 1);
            buck[p1] = (s4.y << BSH) | (d4.y & (BNODES - 1));
            int p2 = atomicAdd(&cur[d4.z >> BSH], 1);
            buck[p2] = (s4.z << BSH) | (d4.z & (BNODES - 1));
            int p3 = atomicAdd(&cur[d4.w >> BSH], 1);
            buck[p3] = (s4.w << BSH) | (d4.w & (BNODES - 1));
        } else {
            for (int e = e0; e < end; ++e) {
                int d = dst[e];
                int pos = atomicAdd(&cur[d >> BSH], 1);
                buck[pos] = (src[e] << BSH) | (d & (BNODES - 1));
            }
        }
    }
}

__global__ __launch_bounds__(256) void bucket_deg_kernel(const int* __restrict__ buck,
                                                         const int* __restrict__ tmp,
                                                         const int* __restrict__ bscan,
                                                         int* __restrict__ deg,
                                                         float* __restrict__ dinv,
                                                         int E, int N, int NB) {
    __shared__ int cnt[BNODES];
    int k = blockIdx.x;
    if (threadIdx.x < BNODES) cnt[threadIdx.x] = 0;
    __syncthreads();
    int i0 = k * NBLK;
    int bs = tmp[i0] + bscan[i0 >> 10];
    int be = E;
    if (k + 1 < NB) {
        int i1 = (k + 1) * NBLK;
        be = tmp[i1] + bscan[i1 >> 10];
    }
    for (int e = bs + threadIdx.x; e < be; e += 256)
        atomicAdd(&cnt[buck[e] & (BNODES - 1)], 1);
    __syncthreads();
    int node0 = k << BSH;
    int i = node0 + threadIdx.x;
    if (threadIdx.x < BNODES && i < N) {
        int c = cnt[threadIdx.x];
        deg[i] = c;
        dinv[i] = rsqrtf((float)(c + 1));  // +1 self loop
    }
}

__global__ __launch_bounds__(256) void bucket_fill_kernel(const int* __restrict__ buck,
                                                          const int* __restrict__ tmp,
                                                          const int* __restrict__ bscan,
                                                          const int* __restrict__ tmpB,
                                                          const int* __restrict__ bscanB,
                                                          int* __restrict__ csr,
                                                          int E, int N, int NB) {
    __shared__ int lrow[BNODES];
    __shared__ int lcur[BNODES];
    int k = blockIdx.x;
    int node0 = k << BSH;
    if (threadIdx.x < BNODES) {
        lcur[threadIdx.x] = 0;
        int i = node0 + threadIdx.x;
        lrow[threadIdx.x] = (i < N) ? (tmpB[i] + bscanB[i >> 10]) : 0;
    }
    __syncthreads();
    int i0 = k * NBLK;
    int bs = tmp[i0] + bscan[i0 >> 10];
    int be = E;
    if (k + 1 < NB) {
        int i1 = (k + 1) * NBLK;
        be = tmp[i1] + bscan[i1 >> 10];
    }
    for (int e = bs + threadIdx.x; e < be; e += 256) {
        int p = buck[e];
        int li = p & (BNODES - 1);
        int pos = lrow[li] + atomicAdd(&lcur[li], 1);
        csr[pos] = p >> BSH;
    }
}

// ---------------- MFMA GEMM (layer 1 only): g1 = half((x @ W1) * dinv) ----------------

__device__ __forceinline__ int swz(int p, int r) { return (p ^ ((r >> 1) & 3)) << 4; }

template <bool AF32, int K, int BN>
__global__ __launch_bounds__(256) void gemm_mfma_kernel(const void* __restrict__ Aptr,
                                                        const __half* __restrict__ Bt,
                                                        const float* __restrict__ dinv,
                                                        __half* __restrict__ C,
                                                        int M) {
    constexpr int NT = BN / 16;
    __shared__ half8 Ash[64 * 4];   // 64 rows x 64B
    __shared__ half8 Bsh[BN * 4];   // BN cols x 64B
    char* Ab = (char*)Ash;
    char* Bb = (char*)Bsh;
    int tid = threadIdx.x;
    int w = tid >> 6;
    int l = tid & 63;
    int row0 = blockIdx.x * 64;
    int sr = tid >> 2, sp = tid & 3;   // staging row / k-plane
    int fr = l & 15, fp = l >> 4;      // fragment row(col) / k-plane
    int arow = w * 16 + fr;
    int a_off = arow * 64 + swz(fp, arow);

    floatx4 acc[NT];
#pragma unroll
    for (int c = 0; c < NT; ++c) acc[c] = (floatx4){0.f, 0.f, 0.f, 0.f};

    for (int k0 = 0; k0 < K; k0 += 32) {
        half8 av = {};
        int gr = row0 + sr;
        if (gr < M) {
            if constexpr (AF32) {
                const float* A = (const float*)Aptr;
                float4 f0 = *(const float4*)(A + (size_t)gr * K + k0 + sp * 8);
                float4 f1 = *(const float4*)(A + (size_t)gr * K + k0 + sp * 8 + 4);
                av[0] = (_Float16)f0.x; av[1] = (_Float16)f0.y;
                av[2] = (_Float16)f0.z; av[3] = (_Float16)f0.w;
                av[4] = (_Float16)f1.x; av[5] = (_Float16)f1.y;
                av[6] = (_Float16)f1.z; av[7] = (_Float16)f1.w;
            } else {
                const __half* A = (const __half*)Aptr;
                av = *(const half8*)(A + (size_t)gr * K + k0 + sp * 8);
            }
        }
        *(half8*)(Ab + sr * 64 + swz(sp, sr)) = av;
        if (tid < BN * 4) {
            int n = tid >> 2, p = tid & 3;
            half8 bv = *(const half8*)(Bt + (size_t)n * K + k0 + p * 8);
            *(half8*)(Bb + n * 64 + swz(p, n)) = bv;
        }
        __syncthreads();
        half8 a = *(const half8*)(Ab + a_off);
#pragma unroll
        for (int c = 0; c < NT; ++c) {
            int col = c * 16 + fr;
            half8 b = *(const half8*)(Bb + col * 64 + swz(fp, col));
            acc[c] = __builtin_amdgcn_mfma_f32_16x16x32_f16(a, b, acc[c], 0, 0, 0);
        }
        __syncthreads();
    }
#pragma unroll
    for (int i = 0; i < 4; ++i) {
        int r = row0 + w * 16 + fp * 4 + i;
        if (r < M) {
            float dn = dinv[r];
#pragma unroll
            for (int c = 0; c < NT; ++c)
                C[(size_t)r * BN + c * 16 + fr] = __float2half(acc[c][i] * dn);
        }
    }
}

// ---------------- gather helpers ----------------

__device__ __forceinline__ void acc_row16(const __half* __restrict__ base, float* a) {
    uint4 raw = *reinterpret_cast<const uint4*>(base);
    float2 f0 = __half22float2(*reinterpret_cast<const __half2*>(&raw.x));
    float2 f1 = __half22float2(*reinterpret_cast<const __half2*>(&raw.y));
    float2 f2 = __half22float2(*reinterpret_cast<const __half2*>(&raw.z));
    float2 f3 = __half22float2(*reinterpret_cast<const __half2*>(&raw.w));
    a[0] += f0.x; a[1] += f0.y; a[2] += f1.x; a[3] += f1.y;
    a[4] += f2.x; a[5] += f2.y; a[6] += f3.x; a[7] += f3.y;
}

// packed fp16 accumulate: 4 v_pk_add_f16 per 16B row chunk
__device__ __forceinline__ void acc_pk(const __half* __restrict__ base, __half2* c2) {
    uint4 raw = *reinterpret_cast<const uint4*>(base);
    c2[0] = __hadd2(c2[0], *reinterpret_cast<const __half2*>(&raw.x));
    c2[1] = __hadd2(c2[1], *reinterpret_cast<const __half2*>(&raw.y));
    c2[2] = __hadd2(c2[2], *reinterpret_cast<const __half2*>(&raw.z));
    c2[3] = __hadd2(c2[3], *reinterpret_cast<const __half2*>(&raw.w));
}

__device__ __forceinline__ void flush_pk(__half2* c2, float* a) {
#pragma unroll
    for (int j = 0; j < 4; ++j) {
        float2 f = __half22float2(c2[j]);
        a[2 * j] += f.x;
        a[2 * j + 1] += f.y;
        c2[j] = __float2half2_rn(0.f);
    }
}

// ---------------- Aggregation layer 1 + fused layer-2 GEMM ----------------
// wave per node; 8 edge-groups x 8 lanes x 16B. fp16 packed accumulate,
// flushed to f32 every <=8 adds. Epilogue: bias+relu -> h1 row (f32) in LDS,
// then all 64 lanes compute g2 = half((h1 @ W2) * dinv) directly.

__global__ __launch_bounds__(256) void agg1_fused_kernel(const __half* __restrict__ g1,
                                                         const int* __restrict__ tmpB,
                                                         const int* __restrict__ bscanB,
                                                         const int* __restrict__ deg,
                                                         const int* __restrict__ csr,
                                                         const float* __restrict__ dinv,
                                                         const float* __restrict__ b1,
                                                         const __half* __restrict__ W2t,
                                                         __half* __restrict__ g2, int n) {
    __shared__ float hrow[4][64];
    int node = (blockIdx.x * 256 + threadIdx.x) >> 6;
    int w = (threadIdx.x >> 6) & 3;
    int lane = threadIdx.x & 63;
    int g = lane >> 3;        // edge group 0..7
    int f8 = lane & 7;        // 16B feature chunk 0..7
    if (node >= n) return;
    int start = tmpB[node] + bscanB[node >> 10];
    int end = start + deg[node];
    float a[8];
#pragma unroll
    for (int j = 0; j < 8; ++j) a[j] = 0.f;
    if (g == 0)  // self loop counted once (f32 path)
        acc_row16(g1 + ((size_t)node << 6) + f8 * 8, a);
    __half2 c2[4];
#pragma unroll
    for (int j = 0; j < 4; ++j) c2[j] = __float2half2_rn(0.f);
    int e = start;
    for (; e + 64 <= end; e += 64) {  // 8 rounds, then flush (<=8 fp16 adds)
#pragma unroll
        for (int r = 0; r < 8; ++r) {
            int s = csr[e + r * 8 + g];
            acc_pk(g1 + ((size_t)s << 6) + f8 * 8, c2);
        }
        flush_pk(c2, a);
    }
    for (; e + 8 <= end; e += 8) {  // <=7 more adds
        int s = csr[e + g];
        acc_pk(g1 + ((size_t)s << 6) + f8 * 8, c2);
    }
    if (e + g < end) {
        int s = csr[e + g];
        acc_pk(g1 + ((size_t)s << 6) + f8 * 8, c2);
    }
    flush_pk(c2, a);
    // fold 8 edge groups
#pragma unroll
    for (int j = 0; j < 8; ++j) a[j] += __shfl_xor(a[j], 8);
#pragma unroll
    for (int j = 0; j < 8; ++j) a[j] += __shfl_xor(a[j], 16);
#pragma unroll
    for (int j = 0; j < 8; ++j) a[j] += __shfl_xor(a[j], 32);
    float dn = dinv[node];
    if (g == 0) {  // bias + relu, stash f32 h1 row in this wave's LDS slice
        float4 bl = *reinterpret_cast<const float4*>(b1 + f8 * 8);
        float4 bh = *reinterpret_cast<const float4*>(b1 + f8 * 8 + 4);
        float4 h0, h1v;
        h0.x = fmaxf(a[0] * dn + bl.x, 0.f);
        h0.y = fmaxf(a[1] * dn + bl.y, 0.f);
        h0.z = fmaxf(a[2] * dn + bl.z, 0.f);
        h0.w = fmaxf(a[3] * dn + bl.w, 0.f);
        h1v.x = fmaxf(a[4] * dn + bh.x, 0.f);
        h1v.y = fmaxf(a[5] * dn + bh.y, 0.f);
        h1v.z = fmaxf(a[6] * dn + bh.z, 0.f);
        h1v.w = fmaxf(a[7] * dn + bh.w, 0.f);
        *reinterpret_cast<float4*>(&hrow[w][f8 * 8]) = h0;
        *reinterpret_cast<float4*>(&hrow[w][f8 * 8 + 4]) = h1v;
    }
    // fused gemm2: lane l -> out feat j=l&31, k-half = l>>5; intra-wave LDS
    // handoff (ds_write -> ds_read ordered by lgkmcnt within the wave).
    int j = lane & 31;
    int kh = (lane >> 5) * 32;
    float part = 0.f;
#pragma unroll
    for (int c = 0; c < 4; ++c) {
        half8 wv = *(const half8*)(W2t + j * 64 + kh + c * 8);
        float4 p0 = *reinterpret_cast<const float4*>(&hrow[w][kh + c * 8]);
        float4 p1 = *reinterpret_cast<const float4*>(&hrow[w][kh + c * 8 + 4]);
        part += p0.x * (float)wv[0] + p0.y * (float)wv[1] +
                p0.z * (float)wv[2] + p0.w * (float)wv[3] +
                p1.x * (float)wv[4] + p1.y * (float)wv[5] +
                p1.z * (float)wv[6] + p1.w * (float)wv[7];
    }
    part += __shfl_xor(part, 32);
    if (lane < 32)
        g2[((size_t)node << 5) + lane] = __float2half(part * dn);
}

// ---------------- Aggregation layer 2 + pooling: wave per node ----------------
// 64 lanes = 16 edge-groups x 4 lanes (32-feat row = 4 x 16B).

__global__ __launch_bounds__(256) void agg2_pool_kernel(const __half* __restrict__ g2,
                                                        const int* __restrict__ tmpB,
                                                        const int* __restrict__ bscanB,
                                                        const int* __restrict__ deg,
                                                        const int* __restrict__ csr,
                                                        const float* __restrict__ dinv,
                                                        const float* __restrict__ b2,
                                                        float* __restrict__ partials,
                                                        int nblocks, int n) {
    int node = (blockIdx.x * 256 + threadIdx.x) >> 6;
    int w = (threadIdx.x >> 6) & 3;  // wave in block
    int lane = threadIdx.x & 63;
    int g = lane >> 2;       // edge group 0..15
    int f4 = lane & 3;       // 16B feature chunk 0..3
    float a[8];
#pragma unroll
    for (int j = 0; j < 8; ++j) a[j] = 0.f;
    if (node < n) {
        int start = tmpB[node] + bscanB[node >> 10];
        int end = start + deg[node];
        if (g == 0)
            acc_row16(g2 + ((size_t)node << 5) + f4 * 8, a);
        __half2 c2[4];
#pragma unroll
        for (int j = 0; j < 4; ++j) c2[j] = __float2half2_rn(0.f);
        int e = start;
        for (; e + 64 <= end; e += 64) {  // 4 rounds, flush (<=4 fp16 adds)
#pragma unroll
            for (int r = 0; r < 4; ++r) {
                int s = csr[e + r * 16 + g];
                acc_pk(g2 + ((size_t)s << 5) + f4 * 8, c2);
            }
            flush_pk(c2, a);
        }
        for (; e + 16 <= end; e += 16) {  // <=3 more adds
            int s = csr[e + g];
            acc_pk(g2 + ((size_t)s << 5) + f4 * 8, c2);
        }
        if (e + g < end) {
            int s = csr[e + g];
            acc_pk(g2 + ((size_t)s << 5) + f4 * 8, c2);
        }
        flush_pk(c2, a);
#pragma unroll
        for (int j = 0; j < 8; ++j) a[j] += __shfl_xor(a[j], 4);
#pragma unroll
        for (int j = 0; j < 8; ++j) a[j] += __shfl_xor(a[j], 8);
#pragma unroll
        for (int j = 0; j < 8; ++j) a[j] += __shfl_xor(a[j], 16);
#pragma unroll
        for (int j = 0; j < 8; ++j) a[j] += __shfl_xor(a[j], 32);
    }
    __shared__ float sdata[4][32];
    if (g == 0) {
        float relu[8];
        if (node < n) {
            float dn = dinv[node];
#pragma unroll
            for (int j = 0; j < 8; ++j)
                relu[j] = fmaxf(a[j] * dn + b2[f4 * 8 + j], 0.f);
        } else {
#pragma unroll
            for (int j = 0; j < 8; ++j) relu[j] = 0.f;
        }
#pragma unroll
        for (int j = 0; j < 8; ++j) sdata[w][f4 * 8 + j] = relu[j];
    }
    __syncthreads();
    if (threadIdx.x < 32) {
        float s = sdata[0][threadIdx.x] + sdata[1][threadIdx.x] +
                  sdata[2][threadIdx.x] + sdata[3][threadIdx.x];
        partials[threadIdx.x * nblocks + blockIdx.x] = s;
    }
}

// 32 blocks, one per feature; fused FC: atomicAdd into pre-zeroed out[0].
__global__ __launch_bounds__(256) void reduce_fc_kernel(const float* __restrict__ partials,
                                                        int nblocks,
                                                        const float* __restrict__ fcw,
                                                        const float* __restrict__ fcb,
                                                        float* __restrict__ out, int n) {
    int f = blockIdx.x;
    const float* col = partials + (size_t)f * nblocks;
    float s = 0.f;
    for (int i = threadIdx.x; i < nblocks; i += 256) s += col[i];
    __shared__ float red[256];
    red[threadIdx.x] = s;
    __syncthreads();
    for (int ofs = 128; ofs > 0; ofs >>= 1) {
        if (threadIdx.x < ofs) red[threadIdx.x] += red[threadIdx.x + ofs];
        __syncthreads();
    }
    if (threadIdx.x == 0) {
        float v = (float)((double)red[0] / (double)n * (double)fcw[f]);
        if (f == 0) v += fcb[0];
        atomicAdd(out, v);
    }
}

// ---------------- launch ----------------

extern "C" void kernel_launch(void* const* d_in, const int* in_sizes, int n_in,
                              void* d_out, int out_size, void* d_ws, size_t ws_size,
                              hipStream_t stream) {
    const float* x   = (const float*)d_in[0];
    const int*   ei  = (const int*)d_in[1];
    const float* W1  = (const float*)d_in[2];
    const float* b1  = (const float*)d_in[3];
    const float* W2  = (const float*)d_in[4];
    const float* b2  = (const float*)d_in[5];
    const float* fcw = (const float*)d_in[6];
    const float* fcb = (const float*)d_in[7];
    float* out = (float*)d_out;

    const int N = in_sizes[0] / 256;  // 100000
    const int E = in_sizes[1] / 2;    // 3200000
    const int* src = ei;
    const int* dst = ei + E;

    const int NB = (N + BNODES - 1) >> BSH;            // 782 buckets
    const int SC = NB * NBLK;                          // hist entries
    const int CH = (((E + NBLK - 1) / NBLK) + 3) & ~3; // edges/block, x4 aligned
    const int nb2 = (N + 3) / 4;                       // agg2 blocks

    char* ws = (char*)d_ws;
    size_t off = 0;
    auto alloc = [&](size_t bytes) -> void* {
        void* p = ws + off;
        off = (off + bytes + 255) & ~(size_t)255;
        return p;
    };
    int*   tmp      = (int*)alloc((size_t)SC * 4);   // scan1 (bucket offsets)
    int*   bsums    = (int*)alloc(2048);
    int*   bscan    = (int*)alloc(2048);
    int*   tmpB     = (int*)alloc((size_t)N * 4);    // scan2 (row offsets)
    int*   bsumsB   = (int*)alloc(2048);
    int*   bscanB   = (int*)alloc(2048);
    int*   deg      = (int*)alloc((size_t)N * 4);
    float* dinv     = (float*)alloc((size_t)N * 4);
    int*   csr      = (int*)alloc((size_t)E * 4);
    __half* W1t     = (__half*)alloc((size_t)64 * 256 * 2);
    __half* W2t     = (__half*)alloc((size_t)32 * 64 * 2);
    // region P: buck (E int) aliases g1 (N*F1 halves) — buck dead before gemm1
    size_t szP = (size_t)E * 4;
    size_t szG1 = (size_t)N * F1 * 2;
    void* P = alloc(szP > szG1 ? szP : szG1);
    int*    buck = (int*)P;
    __half* g1   = (__half*)P;
    int*   hist_T   = (int*)alloc((size_t)SC * 4);
    __half* g2      = (__half*)alloc((size_t)N * F2 * 2);
    float* partials = (float*)alloc((size_t)F2 * nb2 * 4);

    hipMemsetAsync(out, 0, sizeof(float), stream);

    // ---- CSR build via counting sort + weight prep ----
    bucket_hist_prep_kernel<<<NBLK + 1, 256, 0, stream>>>(dst, hist_T, W1, W2, W1t, W2t, E, CH, NB);
    int nbS = (SC + 1023) / 1024;  // 391
    scan_blocks_kernel<<<nbS, 256, 0, stream>>>(hist_T, tmp, bsums, SC);
    scan_sums_kernel<<<1, 512, 0, stream>>>(bsums, bscan, nbS);
    bucket_scatter_kernel<<<NBLK, 256, 0, stream>>>(src, dst, tmp, bscan, buck, E, CH, NB);
    bucket_deg_kernel<<<NB, 256, 0, stream>>>(buck, tmp, bscan, deg, dinv, E, N, NB);
    int nbS2 = (N + 1023) / 1024;  // 98
    scan_blocks_kernel<<<nbS2, 256, 0, stream>>>(deg, tmpB, bsumsB, N);
    scan_sums_kernel<<<1, 512, 0, stream>>>(bsumsB, bscanB, nbS2);
    bucket_fill_kernel<<<NB, 256, 0, stream>>>(buck, tmp, bscan, tmpB, bscanB, csr, E, N, NB);

    int nbG = (N + 63) / 64;  // 1563
    // ---- layer 1 (+ fused layer-2 GEMM in agg epilogue) ----
    gemm_mfma_kernel<true, 256, 64><<<nbG, 256, 0, stream>>>(x, W1t, dinv, g1, N);
    agg1_fused_kernel<<<(N + 3) / 4, 256, 0, stream>>>(g1, tmpB, bscanB, deg, csr, dinv, b1, W2t, g2, N);

    // ---- layer 2 aggregation + pooling ----
    agg2_pool_kernel<<<nb2, 256, 0, stream>>>(g2, tmpB, bscanB, deg, csr, dinv, b2, partials, nb2, N);

    reduce_fc_kernel<<<F2, 256, 0, stream>>>(partials, nb2, fcw, fcb, out, N);
}

// Round 10
// 265.663 us; speedup vs baseline: 1.0717x; 1.0717x over previous
//
#include <hip/hip_runtime.h>
#include <hip/hip_fp16.h>

#ifndef F1
#define F1 64
#define F2 32
#endif

#define NBLK 512     // blocks for bucket hist/scatter passes
#define BSH  7       // bucket = dst >> 7  (128 nodes per bucket)
#define BNODES 128

typedef _Float16 half8 __attribute__((ext_vector_type(8)));
typedef float floatx4 __attribute__((ext_vector_type(4)));

// ---------------- scans ----------------
__global__ __launch_bounds__(256) void scan_blocks_kernel(const int* __restrict__ in,
                                                          int* __restrict__ tmp,
                                                          int* __restrict__ blk_sums, int n) {
    __shared__ int sdata[256];
    int t = threadIdx.x;
    int base = blockIdx.x * 1024 + t * 4;
    int v[4];
#pragma unroll
    for (int j = 0; j < 4; ++j) v[j] = (base + j < n) ? in[base + j] : 0;
    int mysum = v[0] + v[1] + v[2] + v[3];
    sdata[t] = mysum;
    __syncthreads();
    for (int ofs = 1; ofs < 256; ofs <<= 1) {
        int val = (t >= ofs) ? sdata[t - ofs] : 0;
        __syncthreads();
        sdata[t] += val;
        __syncthreads();
    }
    int incl = sdata[t];
    int excl = incl - mysum;
    if (t == 255) blk_sums[blockIdx.x] = incl;
    int run = excl;
#pragma unroll
    for (int j = 0; j < 4; ++j) {
        if (base + j < n) tmp[base + j] = run;
        run += v[j];
    }
}

__global__ __launch_bounds__(512) void scan_sums_kernel(const int* __restrict__ blk_sums,
                                                        int* __restrict__ blk_scanned, int nb) {
    __shared__ int sdata[512];
    int t = threadIdx.x;
    int mine = (t < nb) ? blk_sums[t] : 0;
    sdata[t] = mine;
    __syncthreads();
    for (int ofs = 1; ofs < 512; ofs <<= 1) {
        int val = (t >= ofs) ? sdata[t - ofs] : 0;
        __syncthreads();
        sdata[t] += val;
        __syncthreads();
    }
    blk_scanned[t] = sdata[t] - mine;  // exclusive
}

// ---------------- bucket passes (counting sort by dst>>BSH) ----------------

__global__ __launch_bounds__(256) void bucket_hist_prep_kernel(const int* __restrict__ dst,
                                                               int* __restrict__ hist_T,
                                                               const float* __restrict__ W1,
                                                               const float* __restrict__ W2,
                                                               __half* __restrict__ W1t,
                                                               __half* __restrict__ W2t,
                                                               int E, int CH, int NB) {
    int b = blockIdx.x;
    if (b == NBLK) {  // weight prep: Wt[n][k] = half(W[k][n])
        for (int e = threadIdx.x; e < 64 * 256; e += 256) {
            int n = e >> 8, k = e & 255;
            W1t[e] = __float2half(W1[k * 64 + n]);
        }
        for (int e = threadIdx.x; e < 32 * 64; e += 256) {
            int n = e >> 6, k = e & 63;
            W2t[e] = __float2half(W2[k * 32 + n]);
        }
        return;
    }
    __shared__ int lh[1024];
    for (int i = threadIdx.x; i < NB; i += 256) lh[i] = 0;
    __syncthreads();
    int start = b * CH, end = min(E, start + CH);
    for (int e0 = start + threadIdx.x * 4; e0 < end; e0 += 1024) {
        if (e0 + 4 <= end) {
            int4 d4 = *reinterpret_cast<const int4*>(dst + e0);
            atomicAdd(&lh[d4.x >> BSH], 1);
            atomicAdd(&lh[d4.y >> BSH], 1);
            atomicAdd(&lh[d4.z >> BSH], 1);
            atomicAdd(&lh[d4.w >> BSH], 1);
        } else {
            for (int e = e0; e < end; ++e) atomicAdd(&lh[dst[e] >> BSH], 1);
        }
    }
    __syncthreads();
    for (int k = threadIdx.x; k < NB; k += 256)
        hist_T[k * NBLK + b] = lh[k];
}

__global__ __launch_bounds__(256) void bucket_scatter_kernel(const int* __restrict__ src,
                                                             const int* __restrict__ dst,
                                                             const int* __restrict__ tmp,
                                                             const int* __restrict__ bscan,
                                                             int* __restrict__ buck,
                                                             int E, int CH, int NB) {
    __shared__ int cur[1024];
    int b = blockIdx.x;
    for (int i = threadIdx.x; i < NB; i += 256) {
        int idx = i * NBLK + b;
        cur[i] = tmp[idx] + bscan[idx >> 10];
    }
    __syncthreads();
    int start = b * CH, end = min(E, start + CH);
    for (int e0 = start + threadIdx.x * 4; e0 < end; e0 += 1024) {
        if (e0 + 4 <= end) {
            int4 s4 = *reinterpret_cast<const int4*>(src + e0);
            int4 d4 = *reinterpret_cast<const int4*>(dst + e0);
            int p0 = atomicAdd(&cur[d4.x >> BSH], 1);
            buck[p0] = (s4.x << BSH) | (d4.x & (BNODES - 1));
            int p1 = atomicAdd(&cur[d4.y >> BSH], 1);
            buck[p1] = (s4.y << BSH) | (d4.y & (BNODES - 1));
            int p2 = atomicAdd(&cur[d4.z >> BSH], 1);
            buck[p2] = (s4.z << BSH) | (d4.z & (BNODES - 1));
            int p3 = atomicAdd(&cur[d4.w >> BSH], 1);
            buck[p3] = (s4.w << BSH) | (d4.w & (BNODES - 1));
        } else {
            for (int e = e0; e < end; ++e) {
                int d = dst[e];
                int pos = atomicAdd(&cur[d >> BSH], 1);
                buck[pos] = (src[e] << BSH) | (d & (BNODES - 1));
            }
        }
    }
}

__global__ __launch_bounds__(256) void bucket_deg_kernel(const int* __restrict__ buck,
                                                         const int* __restrict__ tmp,
                                                         const int* __restrict__ bscan,
                                                         int* __restrict__ deg,
                                                         float* __restrict__ dinv,
                                                         int E, int N, int NB) {
    __shared__ int cnt[BNODES];
    int k = blockIdx.x;
    if (threadIdx.x < BNODES) cnt[threadIdx.x] = 0;
    __syncthreads();
    int i0 = k * NBLK;
    int bs = tmp[i0] + bscan[i0 >> 10];
    int be = E;
    if (k + 1 < NB) {
        int i1 = (k + 1) * NBLK;
        be = tmp[i1] + bscan[i1 >> 10];
    }
    for (int e = bs + threadIdx.x; e < be; e += 256)
        atomicAdd(&cnt[buck[e] & (BNODES - 1)], 1);
    __syncthreads();
    int node0 = k << BSH;
    int i = node0 + threadIdx.x;
    if (threadIdx.x < BNODES && i < N) {
        int c = cnt[threadIdx.x];
        deg[i] = c;
        dinv[i] = rsqrtf((float)(c + 1));  // +1 self loop
    }
}

__global__ __launch_bounds__(256) void bucket_fill_kernel(const int* __restrict__ buck,
                                                          const int* __restrict__ tmp,
                                                          const int* __restrict__ bscan,
                                                          const int* __restrict__ tmpB,
                                                          const int* __restrict__ bscanB,
                                                          int* __restrict__ csr,
                                                          int E, int N, int NB) {
    __shared__ int lrow[BNODES];
    __shared__ int lcur[BNODES];
    int k = blockIdx.x;
    int node0 = k << BSH;
    if (threadIdx.x < BNODES) {
        lcur[threadIdx.x] = 0;
        int i = node0 + threadIdx.x;
        lrow[threadIdx.x] = (i < N) ? (tmpB[i] + bscanB[i >> 10]) : 0;
    }
    __syncthreads();
    int i0 = k * NBLK;
    int bs = tmp[i0] + bscan[i0 >> 10];
    int be = E;
    if (k + 1 < NB) {
        int i1 = (k + 1) * NBLK;
        be = tmp[i1] + bscan[i1 >> 10];
    }
    for (int e = bs + threadIdx.x; e < be; e += 256) {
        int p = buck[e];
        int li = p & (BNODES - 1);
        int pos = lrow[li] + atomicAdd(&lcur[li], 1);
        csr[pos] = p >> BSH;
    }
}

// ---------------- MFMA GEMM (layer 1): g1 = half((x @ W1) * dinv) ----------------

__device__ __forceinline__ int swz(int p, int r) { return (p ^ ((r >> 1) & 3)) << 4; }

template <bool AF32, int K, int BN>
__global__ __launch_bounds__(256) void gemm_mfma_kernel(const void* __restrict__ Aptr,
                                                        const __half* __restrict__ Bt,
                                                        const float* __restrict__ dinv,
                                                        __half* __restrict__ C,
                                                        int M) {
    constexpr int NT = BN / 16;
    __shared__ half8 Ash[64 * 4];   // 64 rows x 64B
    __shared__ half8 Bsh[BN * 4];   // BN cols x 64B
    char* Ab = (char*)Ash;
    char* Bb = (char*)Bsh;
    int tid = threadIdx.x;
    int w = tid >> 6;
    int l = tid & 63;
    int row0 = blockIdx.x * 64;
    int sr = tid >> 2, sp = tid & 3;   // staging row / k-plane
    int fr = l & 15, fp = l >> 4;      // fragment row(col) / k-plane
    int arow = w * 16 + fr;
    int a_off = arow * 64 + swz(fp, arow);

    floatx4 acc[NT];
#pragma unroll
    for (int c = 0; c < NT; ++c) acc[c] = (floatx4){0.f, 0.f, 0.f, 0.f};

    for (int k0 = 0; k0 < K; k0 += 32) {
        half8 av = {};
        int gr = row0 + sr;
        if (gr < M) {
            if constexpr (AF32) {
                const float* A = (const float*)Aptr;
                float4 f0 = *(const float4*)(A + (size_t)gr * K + k0 + sp * 8);
                float4 f1 = *(const float4*)(A + (size_t)gr * K + k0 + sp * 8 + 4);
                av[0] = (_Float16)f0.x; av[1] = (_Float16)f0.y;
                av[2] = (_Float16)f0.z; av[3] = (_Float16)f0.w;
                av[4] = (_Float16)f1.x; av[5] = (_Float16)f1.y;
                av[6] = (_Float16)f1.z; av[7] = (_Float16)f1.w;
            } else {
                const __half* A = (const __half*)Aptr;
                av = *(const half8*)(A + (size_t)gr * K + k0 + sp * 8);
            }
        }
        *(half8*)(Ab + sr * 64 + swz(sp, sr)) = av;
        if (tid < BN * 4) {
            int n = tid >> 2, p = tid & 3;
            half8 bv = *(const half8*)(Bt + (size_t)n * K + k0 + p * 8);
            *(half8*)(Bb + n * 64 + swz(p, n)) = bv;
        }
        __syncthreads();
        half8 a = *(const half8*)(Ab + a_off);
#pragma unroll
        for (int c = 0; c < NT; ++c) {
            int col = c * 16 + fr;
            half8 b = *(const half8*)(Bb + col * 64 + swz(fp, col));
            acc[c] = __builtin_amdgcn_mfma_f32_16x16x32_f16(a, b, acc[c], 0, 0, 0);
        }
        __syncthreads();
    }
#pragma unroll
    for (int i = 0; i < 4; ++i) {
        int r = row0 + w * 16 + fp * 4 + i;
        if (r < M) {
            float dn = dinv[r];
#pragma unroll
            for (int c = 0; c < NT; ++c)
                C[(size_t)r * BN + c * 16 + fr] = __float2half(acc[c][i] * dn);
        }
    }
}

// ---------------- gather helpers ----------------

__device__ __forceinline__ void acc_row16(const __half* __restrict__ base, float* a) {
    uint4 raw = *reinterpret_cast<const uint4*>(base);
    float2 f0 = __half22float2(*reinterpret_cast<const __half2*>(&raw.x));
    float2 f1 = __half22float2(*reinterpret_cast<const __half2*>(&raw.y));
    float2 f2 = __half22float2(*reinterpret_cast<const __half2*>(&raw.z));
    float2 f3 = __half22float2(*reinterpret_cast<const __half2*>(&raw.w));
    a[0] += f0.x; a[1] += f0.y; a[2] += f1.x; a[3] += f1.y;
    a[4] += f2.x; a[5] += f2.y; a[6] += f3.x; a[7] += f3.y;
}

// packed fp16 accumulate from a preloaded 16B chunk: 4 v_pk_add_f16
__device__ __forceinline__ void acc_pk_raw(uint4 raw, __half2* c2) {
    c2[0] = __hadd2(c2[0], *reinterpret_cast<const __half2*>(&raw.x));
    c2[1] = __hadd2(c2[1], *reinterpret_cast<const __half2*>(&raw.y));
    c2[2] = __hadd2(c2[2], *reinterpret_cast<const __half2*>(&raw.z));
    c2[3] = __hadd2(c2[3], *reinterpret_cast<const __half2*>(&raw.w));
}

__device__ __forceinline__ void flush_pk(__half2* c2, float* a) {
#pragma unroll
    for (int j = 0; j < 4; ++j) {
        float2 f = __half22float2(c2[j]);
        a[2 * j] += f.x;
        a[2 * j + 1] += f.y;
        c2[j] = __float2half2_rn(0.f);
    }
}

// ---------------- Aggregation layer 1 + fused layer-2 GEMM ----------------
// wave per node; 8 edge-groups x 8 lanes x 16B. 32-edge superblock keeps 4
// gathers in flight (mean degree = 32); fp16 chains <=4 adds then flush.

__global__ __launch_bounds__(256) void agg1_fused_kernel(const __half* __restrict__ g1,
                                                         const int* __restrict__ tmpB,
                                                         const int* __restrict__ bscanB,
                                                         const int* __restrict__ deg,
                                                         const int* __restrict__ csr,
                                                         const float* __restrict__ dinv,
                                                         const float* __restrict__ b1,
                                                         const __half* __restrict__ W2t,
                                                         __half* __restrict__ g2, int n) {
    __shared__ float hrow[4][64];
    int node = (blockIdx.x * 256 + threadIdx.x) >> 6;
    int w = (threadIdx.x >> 6) & 3;
    int lane = threadIdx.x & 63;
    int g = lane >> 3;        // edge group 0..7
    int f8 = lane & 7;        // 16B feature chunk 0..7
    if (node >= n) return;
    int start = tmpB[node] + bscanB[node >> 10];
    int end = start + deg[node];
    float a[8];
#pragma unroll
    for (int j = 0; j < 8; ++j) a[j] = 0.f;
    if (g == 0)  // self loop counted once (f32 path)
        acc_row16(g1 + ((size_t)node << 6) + f8 * 8, a);
    __half2 c2[4];
#pragma unroll
    for (int j = 0; j < 4; ++j) c2[j] = __float2half2_rn(0.f);
    int e = start;
    for (; e + 32 <= end; e += 32) {  // 4 independent gathers in flight
        int i0 = csr[e + g];
        int i1 = csr[e + 8 + g];
        int i2 = csr[e + 16 + g];
        int i3 = csr[e + 24 + g];
        uint4 r0 = *reinterpret_cast<const uint4*>(g1 + ((size_t)i0 << 6) + f8 * 8);
        uint4 r1 = *reinterpret_cast<const uint4*>(g1 + ((size_t)i1 << 6) + f8 * 8);
        uint4 r2 = *reinterpret_cast<const uint4*>(g1 + ((size_t)i2 << 6) + f8 * 8);
        uint4 r3 = *reinterpret_cast<const uint4*>(g1 + ((size_t)i3 << 6) + f8 * 8);
        acc_pk_raw(r0, c2);
        acc_pk_raw(r1, c2);
        acc_pk_raw(r2, c2);
        acc_pk_raw(r3, c2);
        flush_pk(c2, a);  // <=4 fp16 adds per chain
    }
    for (; e + 8 <= end; e += 8) {  // <=3 rounds
        int s = csr[e + g];
        uint4 r = *reinterpret_cast<const uint4*>(g1 + ((size_t)s << 6) + f8 * 8);
        acc_pk_raw(r, c2);
    }
    if (e + g < end) {
        int s = csr[e + g];
        uint4 r = *reinterpret_cast<const uint4*>(g1 + ((size_t)s << 6) + f8 * 8);
        acc_pk_raw(r, c2);
    }
    flush_pk(c2, a);
    // fold 8 edge groups
#pragma unroll
    for (int j = 0; j < 8; ++j) a[j] += __shfl_xor(a[j], 8);
#pragma unroll
    for (int j = 0; j < 8; ++j) a[j] += __shfl_xor(a[j], 16);
#pragma unroll
    for (int j = 0; j < 8; ++j) a[j] += __shfl_xor(a[j], 32);
    float dn = dinv[node];
    if (g == 0) {  // bias + relu, stash f32 h1 row in this wave's LDS slice
        float4 bl = *reinterpret_cast<const float4*>(b1 + f8 * 8);
        float4 bh = *reinterpret_cast<const float4*>(b1 + f8 * 8 + 4);
        float4 h0, h1v;
        h0.x = fmaxf(a[0] * dn + bl.x, 0.f);
        h0.y = fmaxf(a[1] * dn + bl.y, 0.f);
        h0.z = fmaxf(a[2] * dn + bl.z, 0.f);
        h0.w = fmaxf(a[3] * dn + bl.w, 0.f);
        h1v.x = fmaxf(a[4] * dn + bh.x, 0.f);
        h1v.y = fmaxf(a[5] * dn + bh.y, 0.f);
        h1v.z = fmaxf(a[6] * dn + bh.z, 0.f);
        h1v.w = fmaxf(a[7] * dn + bh.w, 0.f);
        *reinterpret_cast<float4*>(&hrow[w][f8 * 8]) = h0;
        *reinterpret_cast<float4*>(&hrow[w][f8 * 8 + 4]) = h1v;
    }
    // fused gemm2: lane l -> out feat j=l&31, k-half = l>>5 (intra-wave LDS)
    int j = lane & 31;
    int kh = (lane >> 5) * 32;
    float part = 0.f;
#pragma unroll
    for (int c = 0; c < 4; ++c) {
        half8 wv = *(const half8*)(W2t + j * 64 + kh + c * 8);
        float4 p0 = *reinterpret_cast<const float4*>(&hrow[w][kh + c * 8]);
        float4 p1 = *reinterpret_cast<const float4*>(&hrow[w][kh + c * 8 + 4]);
        part += p0.x * (float)wv[0] + p0.y * (float)wv[1] +
                p0.z * (float)wv[2] + p0.w * (float)wv[3] +
                p1.x * (float)wv[4] + p1.y * (float)wv[5] +
                p1.z * (float)wv[6] + p1.w * (float)wv[7];
    }
    part += __shfl_xor(part, 32);
    if (lane < 32)
        g2[((size_t)node << 5) + lane] = __float2half(part * dn);
}

// ---------------- Aggregation layer 2 + pooling: wave per node ----------------
// 64 lanes = 16 edge-groups x 4 lanes; 32-edge superblock = 2 gathers in flight.

__global__ __launch_bounds__(256) void agg2_pool_kernel(const __half* __restrict__ g2,
                                                        const int* __restrict__ tmpB,
                                                        const int* __restrict__ bscanB,
                                                        const int* __restrict__ deg,
                                                        const int* __restrict__ csr,
                                                        const float* __restrict__ dinv,
                                                        const float* __restrict__ b2,
                                                        float* __restrict__ partials,
                                                        int nblocks, int n) {
    int node = (blockIdx.x * 256 + threadIdx.x) >> 6;
    int w = (threadIdx.x >> 6) & 3;  // wave in block
    int lane = threadIdx.x & 63;
    int g = lane >> 2;       // edge group 0..15
    int f4 = lane & 3;       // 16B feature chunk 0..3
    float a[8];
#pragma unroll
    for (int j = 0; j < 8; ++j) a[j] = 0.f;
    if (node < n) {
        int start = tmpB[node] + bscanB[node >> 10];
        int end = start + deg[node];
        if (g == 0)
            acc_row16(g2 + ((size_t)node << 5) + f4 * 8, a);
        __half2 c2[4];
#pragma unroll
        for (int j = 0; j < 4; ++j) c2[j] = __float2half2_rn(0.f);
        int e = start;
        for (; e + 32 <= end; e += 32) {
            int i0 = csr[e + g];
            int i1 = csr[e + 16 + g];
            uint4 r0 = *reinterpret_cast<const uint4*>(g2 + ((size_t)i0 << 5) + f4 * 8);
            uint4 r1 = *reinterpret_cast<const uint4*>(g2 + ((size_t)i1 << 5) + f4 * 8);
            acc_pk_raw(r0, c2);
            acc_pk_raw(r1, c2);
            flush_pk(c2, a);
        }
        if (e + 16 <= end) {
            int s = csr[e + g];
            uint4 r = *reinterpret_cast<const uint4*>(g2 + ((size_t)s << 5) + f4 * 8);
            acc_pk_raw(r, c2);
            e += 16;
        }
        if (e + g < end) {
            int s = csr[e + g];
            uint4 r = *reinterpret_cast<const uint4*>(g2 + ((size_t)s << 5) + f4 * 8);
            acc_pk_raw(r, c2);
        }
        flush_pk(c2, a);
#pragma unroll
        for (int j = 0; j < 8; ++j) a[j] += __shfl_xor(a[j], 4);
#pragma unroll
        for (int j = 0; j < 8; ++j) a[j] += __shfl_xor(a[j], 8);
#pragma unroll
        for (int j = 0; j < 8; ++j) a[j] += __shfl_xor(a[j], 16);
#pragma unroll
        for (int j = 0; j < 8; ++j) a[j] += __shfl_xor(a[j], 32);
    }
    __shared__ float sdata[4][32];
    if (g == 0) {
        float relu[8];
        if (node < n) {
            float dn = dinv[node];
#pragma unroll
            for (int j = 0; j < 8; ++j)
                relu[j] = fmaxf(a[j] * dn + b2[f4 * 8 + j], 0.f);
        } else {
#pragma unroll
            for (int j = 0; j < 8; ++j) relu[j] = 0.f;
        }
#pragma unroll
        for (int j = 0; j < 8; ++j) sdata[w][f4 * 8 + j] = relu[j];
    }
    __syncthreads();
    if (threadIdx.x < 32) {
        float s = sdata[0][threadIdx.x] + sdata[1][threadIdx.x] +
                  sdata[2][threadIdx.x] + sdata[3][threadIdx.x];
        partials[threadIdx.x * nblocks + blockIdx.x] = s;
    }
}

// 32 blocks, one per feature; fused FC: atomicAdd into pre-zeroed out[0].
__global__ __launch_bounds__(256) void reduce_fc_kernel(const float* __restrict__ partials,
                                                        int nblocks,
                                                        const float* __restrict__ fcw,
                                                        const float* __restrict__ fcb,
                                                        float* __restrict__ out, int n) {
    int f = blockIdx.x;
    const float* col = partials + (size_t)f * nblocks;
    float s = 0.f;
    for (int i = threadIdx.x; i < nblocks; i += 256) s += col[i];
    __shared__ float red[256];
    red[threadIdx.x] = s;
    __syncthreads();
    for (int ofs = 128; ofs > 0; ofs >>= 1) {
        if (threadIdx.x < ofs) red[threadIdx.x] += red[threadIdx.x + ofs];
        __syncthreads();
    }
    if (threadIdx.x == 0) {
        float v = (float)((double)red[0] / (double)n * (double)fcw[f]);
        if (f == 0) v += fcb[0];
        atomicAdd(out, v);
    }
}

// ---------------- launch ----------------

extern "C" void kernel_launch(void* const* d_in, const int* in_sizes, int n_in,
                              void* d_out, int out_size, void* d_ws, size_t ws_size,
                              hipStream_t stream) {
    const float* x   = (const float*)d_in[0];
    const int*   ei  = (const int*)d_in[1];
    const float* W1  = (const float*)d_in[2];
    const float* b1  = (const float*)d_in[3];
    const float* W2  = (const float*)d_in[4];
    const float* b2  = (const float*)d_in[5];
    const float* fcw = (const float*)d_in[6];
    const float* fcb = (const float*)d_in[7];
    float* out = (float*)d_out;

    const int N = in_sizes[0] / 256;  // 100000
    const int E = in_sizes[1] / 2;    // 3200000
    const int* src = ei;
    const int* dst = ei + E;

    const int NB = (N + BNODES - 1) >> BSH;            // 782 buckets
    const int SC = NB * NBLK;                          // hist entries
    const int CH = (((E + NBLK - 1) / NBLK) + 3) & ~3; // edges/block, x4 aligned
    const int nb2 = (N + 3) / 4;                       // agg2 blocks

    char* ws = (char*)d_ws;
    size_t off = 0;
    auto alloc = [&](size_t bytes) -> void* {
        void* p = ws + off;
        off = (off + bytes + 255) & ~(size_t)255;
        return p;
    };
    int*   tmp      = (int*)alloc((size_t)SC * 4);   // scan1 (bucket offsets)
    int*   bsums    = (int*)alloc(2048);
    int*   bscan    = (int*)alloc(2048);
    int*   tmpB     = (int*)alloc((size_t)N * 4);    // scan2 (row offsets)
    int*   bsumsB   = (int*)alloc(2048);
    int*   bscanB   = (int*)alloc(2048);
    int*   deg      = (int*)alloc((size_t)N * 4);
    float* dinv     = (float*)alloc((size_t)N * 4);
    int*   csr      = (int*)alloc((size_t)E * 4);
    __half* W1t     = (__half*)alloc((size_t)64 * 256 * 2);
    __half* W2t     = (__half*)alloc((size_t)32 * 64 * 2);
    // region P: buck (E int) aliases g1 (N*F1 halves) — buck dead before gemm1
    size_t szP = (size_t)E * 4;
    size_t szG1 = (size_t)N * F1 * 2;
    void* P = alloc(szP > szG1 ? szP : szG1);
    int*    buck = (int*)P;
    __half* g1   = (__half*)P;
    int*   hist_T   = (int*)alloc((size_t)SC * 4);
    __half* g2      = (__half*)alloc((size_t)N * F2 * 2);
    float* partials = (float*)alloc((size_t)F2 * nb2 * 4);

    hipMemsetAsync(out, 0, sizeof(float), stream);

    // ---- CSR build via counting sort + weight prep ----
    bucket_hist_prep_kernel<<<NBLK + 1, 256, 0, stream>>>(dst, hist_T, W1, W2, W1t, W2t, E, CH, NB);
    int nbS = (SC + 1023) / 1024;  // 391
    scan_blocks_kernel<<<nbS, 256, 0, stream>>>(hist_T, tmp, bsums, SC);
    scan_sums_kernel<<<1, 512, 0, stream>>>(bsums, bscan, nbS);
    bucket_scatter_kernel<<<NBLK, 256, 0, stream>>>(src, dst, tmp, bscan, buck, E, CH, NB);
    bucket_deg_kernel<<<NB, 256, 0, stream>>>(buck, tmp, bscan, deg, dinv, E, N, NB);
    int nbS2 = (N + 1023) / 1024;  // 98
    scan_blocks_kernel<<<nbS2, 256, 0, stream>>>(deg, tmpB, bsumsB, N);
    scan_sums_kernel<<<1, 512, 0, stream>>>(bsumsB, bscanB, nbS2);
    bucket_fill_kernel<<<NB, 256, 0, stream>>>(buck, tmp, bscan, tmpB, bscanB, csr, E, N, NB);

    int nbG = (N + 63) / 64;  // 1563
    // ---- layer 1 (+ fused layer-2 GEMM in agg epilogue) ----
    gemm_mfma_kernel<true, 256, 64><<<nbG, 256, 0, stream>>>(x, W1t, dinv, g1, N);
    agg1_fused_kernel<<<(N + 3) / 4, 256, 0, stream>>>(g1, tmpB, bscanB, deg, csr, dinv, b1, W2t, g2, N);

    // ---- layer 2 aggregation + pooling ----
    agg2_pool_kernel<<<nb2, 256, 0, stream>>>(g2, tmpB, bscanB, deg, csr, dinv, b2, partials, nb2, N);

    reduce_fc_kernel<<<F2, 256, 0, stream>>>(partials, nb2, fcw, fcb, out, N);
}

// Round 11
// 246.121 us; speedup vs baseline: 1.1568x; 1.0794x over previous
//
#include <hip/hip_runtime.h>
#include <hip/hip_fp16.h>

#ifndef F1
#define F1 64
#define F2 32
#endif

#define NBLK 512     // blocks for bucket hist/scatter passes
#define BSH  7       // bucket = dst >> 7  (128 nodes per bucket)
#define BNODES 128

typedef _Float16 half8 __attribute__((ext_vector_type(8)));
typedef float floatx4 __attribute__((ext_vector_type(4)));

// ---------------- scans ----------------
__global__ __launch_bounds__(256) void scan_blocks_kernel(const int* __restrict__ in,
                                                          int* __restrict__ tmp,
                                                          int* __restrict__ blk_sums, int n) {
    __shared__ int sdata[256];
    int t = threadIdx.x;
    int base = blockIdx.x * 1024 + t * 4;
    int v[4];
#pragma unroll
    for (int j = 0; j < 4; ++j) v[j] = (base + j < n) ? in[base + j] : 0;
    int mysum = v[0] + v[1] + v[2] + v[3];
    sdata[t] = mysum;
    __syncthreads();
    for (int ofs = 1; ofs < 256; ofs <<= 1) {
        int val = (t >= ofs) ? sdata[t - ofs] : 0;
        __syncthreads();
        sdata[t] += val;
        __syncthreads();
    }
    int incl = sdata[t];
    int excl = incl - mysum;
    if (t == 255) blk_sums[blockIdx.x] = incl;
    int run = excl;
#pragma unroll
    for (int j = 0; j < 4; ++j) {
        if (base + j < n) tmp[base + j] = run;
        run += v[j];
    }
}

__global__ __launch_bounds__(512) void scan_sums_kernel(const int* __restrict__ blk_sums,
                                                        int* __restrict__ blk_scanned, int nb) {
    __shared__ int sdata[512];
    int t = threadIdx.x;
    int mine = (t < nb) ? blk_sums[t] : 0;
    sdata[t] = mine;
    __syncthreads();
    for (int ofs = 1; ofs < 512; ofs <<= 1) {
        int val = (t >= ofs) ? sdata[t - ofs] : 0;
        __syncthreads();
        sdata[t] += val;
        __syncthreads();
    }
    blk_scanned[t] = sdata[t] - mine;  // exclusive
}

// ---------------- bucket passes (counting sort by dst>>BSH) ----------------

__global__ __launch_bounds__(256) void bucket_hist_prep_kernel(const int* __restrict__ dst,
                                                               int* __restrict__ hist_T,
                                                               const float* __restrict__ W1,
                                                               const float* __restrict__ W2,
                                                               __half* __restrict__ W1t,
                                                               __half* __restrict__ W2p,
                                                               int E, int CH, int NB) {
    int b = blockIdx.x;
    if (b == NBLK) {  // weight prep
        for (int e = threadIdx.x; e < 64 * 256; e += 256) {
            int n = e >> 8, k = e & 255;
            W1t[e] = __float2half(W1[k * 64 + n]);
        }
        // W2p[c][l][m] = W2[k][j], j=l&31, k=(l>>5)*32 + c*8 + m  (lane-major)
        for (int e = threadIdx.x; e < 4 * 64 * 8; e += 256) {
            int c = e >> 9, rem = e & 511;
            int l = rem >> 3, m = rem & 7;
            int j = l & 31;
            int k = (l >> 5) * 32 + c * 8 + m;
            W2p[e] = __float2half(W2[k * 32 + j]);
        }
        return;
    }
    __shared__ int lh[1024];
    for (int i = threadIdx.x; i < NB; i += 256) lh[i] = 0;
    __syncthreads();
    int start = b * CH, end = min(E, start + CH);
    for (int e0 = start + threadIdx.x * 4; e0 < end; e0 += 1024) {
        if (e0 + 4 <= end) {
            int4 d4 = *reinterpret_cast<const int4*>(dst + e0);
            atomicAdd(&lh[d4.x >> BSH], 1);
            atomicAdd(&lh[d4.y >> BSH], 1);
            atomicAdd(&lh[d4.z >> BSH], 1);
            atomicAdd(&lh[d4.w >> BSH], 1);
        } else {
            for (int e = e0; e < end; ++e) atomicAdd(&lh[dst[e] >> BSH], 1);
        }
    }
    __syncthreads();
    for (int k = threadIdx.x; k < NB; k += 256)
        hist_T[k * NBLK + b] = lh[k];
}

__global__ __launch_bounds__(256) void bucket_scatter_kernel(const int* __restrict__ src,
                                                             const int* __restrict__ dst,
                                                             const int* __restrict__ tmp,
                                                             const int* __restrict__ bscan,
                                                             int* __restrict__ buck,
                                                             int E, int CH, int NB) {
    __shared__ int cur[1024];
    int b = blockIdx.x;
    for (int i = threadIdx.x; i < NB; i += 256) {
        int idx = i * NBLK + b;
        cur[i] = tmp[idx] + bscan[idx >> 10];
    }
    __syncthreads();
    int start = b * CH, end = min(E, start + CH);
    for (int e0 = start + threadIdx.x * 4; e0 < end; e0 += 1024) {
        if (e0 + 4 <= end) {
            int4 s4 = *reinterpret_cast<const int4*>(src + e0);
            int4 d4 = *reinterpret_cast<const int4*>(dst + e0);
            int p0 = atomicAdd(&cur[d4.x >> BSH], 1);
            buck[p0] = (s4.x << BSH) | (d4.x & (BNODES - 1));
            int p1 = atomicAdd(&cur[d4.y >> BSH], 1);
            buck[p1] = (s4.y << BSH) | (d4.y & (BNODES - 1));
            int p2 = atomicAdd(&cur[d4.z >> BSH], 1);
            buck[p2] = (s4.z << BSH) | (d4.z & (BNODES - 1));
            int p3 = atomicAdd(&cur[d4.w >> BSH], 1);
            buck[p3] = (s4.w << BSH) | (d4.w & (BNODES - 1));
        } else {
            for (int e = e0; e < end; ++e) {
                int d = dst[e];
                int pos = atomicAdd(&cur[d >> BSH], 1);
                buck[pos] = (src[e] << BSH) | (d & (BNODES - 1));
            }
        }
    }
}

__global__ __launch_bounds__(256) void bucket_deg_kernel(const int* __restrict__ buck,
                                                         const int* __restrict__ tmp,
                                                         const int* __restrict__ bscan,
                                                         int* __restrict__ deg,
                                                         float* __restrict__ dinv,
                                                         int E, int N, int NB) {
    __shared__ int cnt[BNODES];
    int k = blockIdx.x;
    if (threadIdx.x < BNODES) cnt[threadIdx.x] = 0;
    __syncthreads();
    int i0 = k * NBLK;
    int bs = tmp[i0] + bscan[i0 >> 10];
    int be = E;
    if (k + 1 < NB) {
        int i1 = (k + 1) * NBLK;
        be = tmp[i1] + bscan[i1 >> 10];
    }
    for (int e = bs + threadIdx.x; e < be; e += 256)
        atomicAdd(&cnt[buck[e] & (BNODES - 1)], 1);
    __syncthreads();
    int node0 = k << BSH;
    int i = node0 + threadIdx.x;
    if (threadIdx.x < BNODES && i < N) {
        int c = cnt[threadIdx.x];
        deg[i] = c;
        dinv[i] = rsqrtf((float)(c + 1));  // +1 self loop
    }
}

__global__ __launch_bounds__(256) void bucket_fill_kernel(const int* __restrict__ buck,
                                                          const int* __restrict__ tmp,
                                                          const int* __restrict__ bscan,
                                                          const int* __restrict__ tmpB,
                                                          const int* __restrict__ bscanB,
                                                          int* __restrict__ csr,
                                                          int E, int N, int NB) {
    __shared__ int lrow[BNODES];
    __shared__ int lcur[BNODES];
    int k = blockIdx.x;
    int node0 = k << BSH;
    if (threadIdx.x < BNODES) {
        lcur[threadIdx.x] = 0;
        int i = node0 + threadIdx.x;
        lrow[threadIdx.x] = (i < N) ? (tmpB[i] + bscanB[i >> 10]) : 0;
    }
    __syncthreads();
    int i0 = k * NBLK;
    int bs = tmp[i0] + bscan[i0 >> 10];
    int be = E;
    if (k + 1 < NB) {
        int i1 = (k + 1) * NBLK;
        be = tmp[i1] + bscan[i1 >> 10];
    }
    for (int e = bs + threadIdx.x; e < be; e += 256) {
        int p = buck[e];
        int li = p & (BNODES - 1);
        int pos = lrow[li] + atomicAdd(&lcur[li], 1);
        csr[pos] = p >> BSH;
    }
}

// ---------------- MFMA GEMM (layer 1): g1 = half((x @ W1) * dinv) ----------------

__device__ __forceinline__ int swz(int p, int r) { return (p ^ ((r >> 1) & 3)) << 4; }

template <bool AF32, int K, int BN>
__global__ __launch_bounds__(256) void gemm_mfma_kernel(const void* __restrict__ Aptr,
                                                        const __half* __restrict__ Bt,
                                                        const float* __restrict__ dinv,
                                                        __half* __restrict__ C,
                                                        int M) {
    constexpr int NT = BN / 16;
    __shared__ half8 Ash[64 * 4];   // 64 rows x 64B
    __shared__ half8 Bsh[BN * 4];   // BN cols x 64B
    char* Ab = (char*)Ash;
    char* Bb = (char*)Bsh;
    int tid = threadIdx.x;
    int w = tid >> 6;
    int l = tid & 63;
    int row0 = blockIdx.x * 64;
    int sr = tid >> 2, sp = tid & 3;   // staging row / k-plane
    int fr = l & 15, fp = l >> 4;      // fragment row(col) / k-plane
    int arow = w * 16 + fr;
    int a_off = arow * 64 + swz(fp, arow);

    floatx4 acc[NT];
#pragma unroll
    for (int c = 0; c < NT; ++c) acc[c] = (floatx4){0.f, 0.f, 0.f, 0.f};

    for (int k0 = 0; k0 < K; k0 += 32) {
        half8 av = {};
        int gr = row0 + sr;
        if (gr < M) {
            if constexpr (AF32) {
                const float* A = (const float*)Aptr;
                float4 f0 = *(const float4*)(A + (size_t)gr * K + k0 + sp * 8);
                float4 f1 = *(const float4*)(A + (size_t)gr * K + k0 + sp * 8 + 4);
                av[0] = (_Float16)f0.x; av[1] = (_Float16)f0.y;
                av[2] = (_Float16)f0.z; av[3] = (_Float16)f0.w;
                av[4] = (_Float16)f1.x; av[5] = (_Float16)f1.y;
                av[6] = (_Float16)f1.z; av[7] = (_Float16)f1.w;
            } else {
                const __half* A = (const __half*)Aptr;
                av = *(const half8*)(A + (size_t)gr * K + k0 + sp * 8);
            }
        }
        *(half8*)(Ab + sr * 64 + swz(sp, sr)) = av;
        if (tid < BN * 4) {
            int n = tid >> 2, p = tid & 3;
            half8 bv = *(const half8*)(Bt + (size_t)n * K + k0 + p * 8);
            *(half8*)(Bb + n * 64 + swz(p, n)) = bv;
        }
        __syncthreads();
        half8 a = *(const half8*)(Ab + a_off);
#pragma unroll
        for (int c = 0; c < NT; ++c) {
            int col = c * 16 + fr;
            half8 b = *(const half8*)(Bb + col * 64 + swz(fp, col));
            acc[c] = __builtin_amdgcn_mfma_f32_16x16x32_f16(a, b, acc[c], 0, 0, 0);
        }
        __syncthreads();
    }
#pragma unroll
    for (int i = 0; i < 4; ++i) {
        int r = row0 + w * 16 + fp * 4 + i;
        if (r < M) {
            float dn = dinv[r];
#pragma unroll
            for (int c = 0; c < NT; ++c)
                C[(size_t)r * BN + c * 16 + fr] = __float2half(acc[c][i] * dn);
        }
    }
}

// ---------------- gather helpers ----------------

__device__ __forceinline__ void acc_row16(const __half* __restrict__ base, float* a) {
    uint4 raw = *reinterpret_cast<const uint4*>(base);
    float2 f0 = __half22float2(*reinterpret_cast<const __half2*>(&raw.x));
    float2 f1 = __half22float2(*reinterpret_cast<const __half2*>(&raw.y));
    float2 f2 = __half22float2(*reinterpret_cast<const __half2*>(&raw.z));
    float2 f3 = __half22float2(*reinterpret_cast<const __half2*>(&raw.w));
    a[0] += f0.x; a[1] += f0.y; a[2] += f1.x; a[3] += f1.y;
    a[4] += f2.x; a[5] += f2.y; a[6] += f3.x; a[7] += f3.y;
}

// packed fp16 accumulate from a preloaded 16B chunk: 4 v_pk_add_f16
__device__ __forceinline__ void acc_pk_raw(uint4 raw, __half2* c2) {
    c2[0] = __hadd2(c2[0], *reinterpret_cast<const __half2*>(&raw.x));
    c2[1] = __hadd2(c2[1], *reinterpret_cast<const __half2*>(&raw.y));
    c2[2] = __hadd2(c2[2], *reinterpret_cast<const __half2*>(&raw.z));
    c2[3] = __hadd2(c2[3], *reinterpret_cast<const __half2*>(&raw.w));
}

__device__ __forceinline__ void flush_pk(__half2* c2, float* a) {
#pragma unroll
    for (int j = 0; j < 4; ++j) {
        float2 f = __half22float2(c2[j]);
        a[2 * j] += f.x;
        a[2 * j + 1] += f.y;
        c2[j] = __float2half2_rn(0.f);
    }
}

// ---------------- Aggregation layer 1 + fused layer-2 GEMM ----------------
// wave per node; 8 edge-groups x 8 lanes x 16B. 32-edge superblock keeps 4
// gathers in flight; fp16 chains <=4 adds then flush. Fused gemm2 reads W2p
// in lane-major layout (coalesced 1KB loads).

__global__ __launch_bounds__(256) void agg1_fused_kernel(const __half* __restrict__ g1,
                                                         const int* __restrict__ tmpB,
                                                         const int* __restrict__ bscanB,
                                                         const int* __restrict__ deg,
                                                         const int* __restrict__ csr,
                                                         const float* __restrict__ dinv,
                                                         const float* __restrict__ b1,
                                                         const __half* __restrict__ W2p,
                                                         __half* __restrict__ g2, int n) {
    __shared__ float hrow[4][64];
    int node = (blockIdx.x * 256 + threadIdx.x) >> 6;
    int w = (threadIdx.x >> 6) & 3;
    int lane = threadIdx.x & 63;
    int g = lane >> 3;        // edge group 0..7
    int f8 = lane & 7;        // 16B feature chunk 0..7
    if (node >= n) return;
    int start = tmpB[node] + bscanB[node >> 10];
    int end = start + deg[node];
    float a[8];
#pragma unroll
    for (int j = 0; j < 8; ++j) a[j] = 0.f;
    if (g == 0)  // self loop counted once (f32 path)
        acc_row16(g1 + ((size_t)node << 6) + f8 * 8, a);
    __half2 c2[4];
#pragma unroll
    for (int j = 0; j < 4; ++j) c2[j] = __float2half2_rn(0.f);
    int e = start;
    for (; e + 32 <= end; e += 32) {  // 4 independent gathers in flight
        int i0 = csr[e + g];
        int i1 = csr[e + 8 + g];
        int i2 = csr[e + 16 + g];
        int i3 = csr[e + 24 + g];
        uint4 r0 = *reinterpret_cast<const uint4*>(g1 + ((size_t)i0 << 6) + f8 * 8);
        uint4 r1 = *reinterpret_cast<const uint4*>(g1 + ((size_t)i1 << 6) + f8 * 8);
        uint4 r2 = *reinterpret_cast<const uint4*>(g1 + ((size_t)i2 << 6) + f8 * 8);
        uint4 r3 = *reinterpret_cast<const uint4*>(g1 + ((size_t)i3 << 6) + f8 * 8);
        acc_pk_raw(r0, c2);
        acc_pk_raw(r1, c2);
        acc_pk_raw(r2, c2);
        acc_pk_raw(r3, c2);
        flush_pk(c2, a);  // <=4 fp16 adds per chain
    }
    for (; e + 8 <= end; e += 8) {  // <=3 rounds
        int s = csr[e + g];
        uint4 r = *reinterpret_cast<const uint4*>(g1 + ((size_t)s << 6) + f8 * 8);
        acc_pk_raw(r, c2);
    }
    if (e + g < end) {
        int s = csr[e + g];
        uint4 r = *reinterpret_cast<const uint4*>(g1 + ((size_t)s << 6) + f8 * 8);
        acc_pk_raw(r, c2);
    }
    flush_pk(c2, a);
    // fold 8 edge groups
#pragma unroll
    for (int j = 0; j < 8; ++j) a[j] += __shfl_xor(a[j], 8);
#pragma unroll
    for (int j = 0; j < 8; ++j) a[j] += __shfl_xor(a[j], 16);
#pragma unroll
    for (int j = 0; j < 8; ++j) a[j] += __shfl_xor(a[j], 32);
    float dn = dinv[node];
    if (g == 0) {  // bias + relu, stash f32 h1 row in this wave's LDS slice
        float4 bl = *reinterpret_cast<const float4*>(b1 + f8 * 8);
        float4 bh = *reinterpret_cast<const float4*>(b1 + f8 * 8 + 4);
        float4 h0, h1v;
        h0.x = fmaxf(a[0] * dn + bl.x, 0.f);
        h0.y = fmaxf(a[1] * dn + bl.y, 0.f);
        h0.z = fmaxf(a[2] * dn + bl.z, 0.f);
        h0.w = fmaxf(a[3] * dn + bl.w, 0.f);
        h1v.x = fmaxf(a[4] * dn + bh.x, 0.f);
        h1v.y = fmaxf(a[5] * dn + bh.y, 0.f);
        h1v.z = fmaxf(a[6] * dn + bh.z, 0.f);
        h1v.w = fmaxf(a[7] * dn + bh.w, 0.f);
        *reinterpret_cast<float4*>(&hrow[w][f8 * 8]) = h0;
        *reinterpret_cast<float4*>(&hrow[w][f8 * 8 + 4]) = h1v;
    }
    // fused gemm2: lane l -> out feat j=l&31, k-half = l>>5 (intra-wave LDS).
    // W2p is lane-major: load c is fully coalesced (64 lanes x 16B contiguous).
    int kh = (lane >> 5) * 32;
    float part = 0.f;
#pragma unroll
    for (int c = 0; c < 4; ++c) {
        half8 wv = *(const half8*)(W2p + ((c << 6) + lane) * 8);
        float4 p0 = *reinterpret_cast<const float4*>(&hrow[w][kh + c * 8]);
        float4 p1 = *reinterpret_cast<const float4*>(&hrow[w][kh + c * 8 + 4]);
        part += p0.x * (float)wv[0] + p0.y * (float)wv[1] +
                p0.z * (float)wv[2] + p0.w * (float)wv[3] +
                p1.x * (float)wv[4] + p1.y * (float)wv[5] +
                p1.z * (float)wv[6] + p1.w * (float)wv[7];
    }
    part += __shfl_xor(part, 32);
    if (lane < 32)
        g2[((size_t)node << 5) + lane] = __float2half(part * dn);
}

// ---------------- Aggregation layer 2 + pooling: wave per node ----------------
// 64 lanes = 16 edge-groups x 4 lanes; 32-edge superblock = 2 gathers in flight.

__global__ __launch_bounds__(256) void agg2_pool_kernel(const __half* __restrict__ g2,
                                                        const int* __restrict__ tmpB,
                                                        const int* __restrict__ bscanB,
                                                        const int* __restrict__ deg,
                                                        const int* __restrict__ csr,
                                                        const float* __restrict__ dinv,
                                                        const float* __restrict__ b2,
                                                        float* __restrict__ partials,
                                                        int nblocks, int n) {
    int node = (blockIdx.x * 256 + threadIdx.x) >> 6;
    int w = (threadIdx.x >> 6) & 3;  // wave in block
    int lane = threadIdx.x & 63;
    int g = lane >> 2;       // edge group 0..15
    int f4 = lane & 3;       // 16B feature chunk 0..3
    float a[8];
#pragma unroll
    for (int j = 0; j < 8; ++j) a[j] = 0.f;
    if (node < n) {
        int start = tmpB[node] + bscanB[node >> 10];
        int end = start + deg[node];
        if (g == 0)
            acc_row16(g2 + ((size_t)node << 5) + f4 * 8, a);
        __half2 c2[4];
#pragma unroll
        for (int j = 0; j < 4; ++j) c2[j] = __float2half2_rn(0.f);
        int e = start;
        for (; e + 32 <= end; e += 32) {
            int i0 = csr[e + g];
            int i1 = csr[e + 16 + g];
            uint4 r0 = *reinterpret_cast<const uint4*>(g2 + ((size_t)i0 << 5) + f4 * 8);
            uint4 r1 = *reinterpret_cast<const uint4*>(g2 + ((size_t)i1 << 5) + f4 * 8);
            acc_pk_raw(r0, c2);
            acc_pk_raw(r1, c2);
            flush_pk(c2, a);
        }
        if (e + 16 <= end) {
            int s = csr[e + g];
            uint4 r = *reinterpret_cast<const uint4*>(g2 + ((size_t)s << 5) + f4 * 8);
            acc_pk_raw(r, c2);
            e += 16;
        }
        if (e + g < end) {
            int s = csr[e + g];
            uint4 r = *reinterpret_cast<const uint4*>(g2 + ((size_t)s << 5) + f4 * 8);
            acc_pk_raw(r, c2);
        }
        flush_pk(c2, a);
#pragma unroll
        for (int j = 0; j < 8; ++j) a[j] += __shfl_xor(a[j], 4);
#pragma unroll
        for (int j = 0; j < 8; ++j) a[j] += __shfl_xor(a[j], 8);
#pragma unroll
        for (int j = 0; j < 8; ++j) a[j] += __shfl_xor(a[j], 16);
#pragma unroll
        for (int j = 0; j < 8; ++j) a[j] += __shfl_xor(a[j], 32);
    }
    __shared__ float sdata[4][32];
    if (g == 0) {
        float relu[8];
        if (node < n) {
            float dn = dinv[node];
#pragma unroll
            for (int j = 0; j < 8; ++j)
                relu[j] = fmaxf(a[j] * dn + b2[f4 * 8 + j], 0.f);
        } else {
#pragma unroll
            for (int j = 0; j < 8; ++j) relu[j] = 0.f;
        }
#pragma unroll
        for (int j = 0; j < 8; ++j) sdata[w][f4 * 8 + j] = relu[j];
    }
    __syncthreads();
    if (threadIdx.x < 32) {
        float s = sdata[0][threadIdx.x] + sdata[1][threadIdx.x] +
                  sdata[2][threadIdx.x] + sdata[3][threadIdx.x];
        partials[threadIdx.x * nblocks + blockIdx.x] = s;
    }
}

// 32 blocks, one per feature; fused FC: atomicAdd into pre-zeroed out[0].
__global__ __launch_bounds__(256) void reduce_fc_kernel(const float* __restrict__ partials,
                                                        int nblocks,
                                                        const float* __restrict__ fcw,
                                                        const float* __restrict__ fcb,
                                                        float* __restrict__ out, int n) {
    int f = blockIdx.x;
    const float* col = partials + (size_t)f * nblocks;
    float s = 0.f;
    for (int i = threadIdx.x; i < nblocks; i += 256) s += col[i];
    __shared__ float red[256];
    red[threadIdx.x] = s;
    __syncthreads();
    for (int ofs = 128; ofs > 0; ofs >>= 1) {
        if (threadIdx.x < ofs) red[threadIdx.x] += red[threadIdx.x + ofs];
        __syncthreads();
    }
    if (threadIdx.x == 0) {
        float v = (float)((double)red[0] / (double)n * (double)fcw[f]);
        if (f == 0) v += fcb[0];
        atomicAdd(out, v);
    }
}

// ---------------- launch ----------------

extern "C" void kernel_launch(void* const* d_in, const int* in_sizes, int n_in,
                              void* d_out, int out_size, void* d_ws, size_t ws_size,
                              hipStream_t stream) {
    const float* x   = (const float*)d_in[0];
    const int*   ei  = (const int*)d_in[1];
    const float* W1  = (const float*)d_in[2];
    const float* b1  = (const float*)d_in[3];
    const float* W2  = (const float*)d_in[4];
    const float* b2  = (const float*)d_in[5];
    const float* fcw = (const float*)d_in[6];
    const float* fcb = (const float*)d_in[7];
    float* out = (float*)d_out;

    const int N = in_sizes[0] / 256;  // 100000
    const int E = in_sizes[1] / 2;    // 3200000
    const int* src = ei;
    const int* dst = ei + E;

    const int NB = (N + BNODES - 1) >> BSH;            // 782 buckets
    const int SC = NB * NBLK;                          // hist entries
    const int CH = (((E + NBLK - 1) / NBLK) + 3) & ~3; // edges/block, x4 aligned
    const int nb2 = (N + 3) / 4;                       // agg2 blocks

    char* ws = (char*)d_ws;
    size_t off = 0;
    auto alloc = [&](size_t bytes) -> void* {
        void* p = ws + off;
        off = (off + bytes + 255) & ~(size_t)255;
        return p;
    };
    int*   tmp      = (int*)alloc((size_t)SC * 4);   // scan1 (bucket offsets)
    int*   bsums    = (int*)alloc(2048);
    int*   bscan    = (int*)alloc(2048);
    int*   tmpB     = (int*)alloc((size_t)N * 4);    // scan2 (row offsets)
    int*   bsumsB   = (int*)alloc(2048);
    int*   bscanB   = (int*)alloc(2048);
    int*   deg      = (int*)alloc((size_t)N * 4);
    float* dinv     = (float*)alloc((size_t)N * 4);
    int*   csr      = (int*)alloc((size_t)E * 4);
    __half* W1t     = (__half*)alloc((size_t)64 * 256 * 2);
    __half* W2p     = (__half*)alloc((size_t)4 * 64 * 8 * 2);
    // region P: buck (E int) aliases g1 (N*F1 halves) — buck dead before gemm1
    size_t szP = (size_t)E * 4;
    size_t szG1 = (size_t)N * F1 * 2;
    void* P = alloc(szP > szG1 ? szP : szG1);
    int*    buck = (int*)P;
    __half* g1   = (__half*)P;
    int*   hist_T   = (int*)alloc((size_t)SC * 4);
    __half* g2      = (__half*)alloc((size_t)N * F2 * 2);
    float* partials = (float*)alloc((size_t)F2 * nb2 * 4);

    hipMemsetAsync(out, 0, sizeof(float), stream);

    // ---- CSR build via counting sort + weight prep ----
    bucket_hist_prep_kernel<<<NBLK + 1, 256, 0, stream>>>(dst, hist_T, W1, W2, W1t, W2p, E, CH, NB);
    int nbS = (SC + 1023) / 1024;  // 391
    scan_blocks_kernel<<<nbS, 256, 0, stream>>>(hist_T, tmp, bsums, SC);
    scan_sums_kernel<<<1, 512, 0, stream>>>(bsums, bscan, nbS);
    bucket_scatter_kernel<<<NBLK, 256, 0, stream>>>(src, dst, tmp, bscan, buck, E, CH, NB);
    bucket_deg_kernel<<<NB, 256, 0, stream>>>(buck, tmp, bscan, deg, dinv, E, N, NB);
    int nbS2 = (N + 1023) / 1024;  // 98
    scan_blocks_kernel<<<nbS2, 256, 0, stream>>>(deg, tmpB, bsumsB, N);
    scan_sums_kernel<<<1, 512, 0, stream>>>(bsumsB, bscanB, nbS2);
    bucket_fill_kernel<<<NB, 256, 0, stream>>>(buck, tmp, bscan, tmpB, bscanB, csr, E, N, NB);

    int nbG = (N + 63) / 64;  // 1563
    // ---- layer 1 (+ fused layer-2 GEMM in agg epilogue) ----
    gemm_mfma_kernel<true, 256, 64><<<nbG, 256, 0, stream>>>(x, W1t, dinv, g1, N);
    agg1_fused_kernel<<<(N + 3) / 4, 256, 0, stream>>>(g1, tmpB, bscanB, deg, csr, dinv, b1, W2p, g2, N);

    // ---- layer 2 aggregation + pooling ----
    agg2_pool_kernel<<<nb2, 256, 0, stream>>>(g2, tmpB, bscanB, deg, csr, dinv, b2, partials, nb2, N);

    reduce_fc_kernel<<<F2, 256, 0, stream>>>(partials, nb2, fcw, fcb, out, N);
}

// Round 12
// 215.935 us; speedup vs baseline: 1.3186x; 1.1398x over previous
//
#include <hip/hip_runtime.h>
#include <hip/hip_fp16.h>

#ifndef F1
#define F1 64
#define F2 32
#endif

#define NBLK 512     // blocks for bucket hist/scatter passes
#define BSH  7       // bucket = dst >> 7  (128 nodes per bucket)
#define BNODES 128

typedef _Float16 half8 __attribute__((ext_vector_type(8)));
typedef float floatx4 __attribute__((ext_vector_type(4)));

// ---------------- scans ----------------
__global__ __launch_bounds__(256) void scan_blocks_kernel(const int* __restrict__ in,
                                                          int* __restrict__ tmp,
                                                          int* __restrict__ blk_sums, int n) {
    __shared__ int sdata[256];
    int t = threadIdx.x;
    int base = blockIdx.x * 1024 + t * 4;
    int v[4];
#pragma unroll
    for (int j = 0; j < 4; ++j) v[j] = (base + j < n) ? in[base + j] : 0;
    int mysum = v[0] + v[1] + v[2] + v[3];
    sdata[t] = mysum;
    __syncthreads();
    for (int ofs = 1; ofs < 256; ofs <<= 1) {
        int val = (t >= ofs) ? sdata[t - ofs] : 0;
        __syncthreads();
        sdata[t] += val;
        __syncthreads();
    }
    int incl = sdata[t];
    int excl = incl - mysum;
    if (t == 255) blk_sums[blockIdx.x] = incl;
    int run = excl;
#pragma unroll
    for (int j = 0; j < 4; ++j) {
        if (base + j < n) tmp[base + j] = run;
        run += v[j];
    }
}

__global__ __launch_bounds__(512) void scan_sums_kernel(const int* __restrict__ blk_sums,
                                                        int* __restrict__ blk_scanned, int nb) {
    __shared__ int sdata[512];
    int t = threadIdx.x;
    int mine = (t < nb) ? blk_sums[t] : 0;
    sdata[t] = mine;
    __syncthreads();
    for (int ofs = 1; ofs < 512; ofs <<= 1) {
        int val = (t >= ofs) ? sdata[t - ofs] : 0;
        __syncthreads();
        sdata[t] += val;
        __syncthreads();
    }
    blk_scanned[t] = sdata[t] - mine;  // exclusive
}

// ---------------- bucket passes (counting sort by dst>>BSH) ----------------

__global__ __launch_bounds__(256) void bucket_hist_prep_kernel(const int* __restrict__ dst,
                                                               int* __restrict__ hist_T,
                                                               const float* __restrict__ W1,
                                                               const float* __restrict__ W2,
                                                               __half* __restrict__ W1t,
                                                               __half* __restrict__ W2t,
                                                               int E, int CH, int NB) {
    int b = blockIdx.x;
    if (b == NBLK) {  // weight prep: Wt[n][k] = half(W[k][n])
        for (int e = threadIdx.x; e < 64 * 256; e += 256) {
            int n = e >> 8, k = e & 255;
            W1t[e] = __float2half(W1[k * 64 + n]);
        }
        for (int e = threadIdx.x; e < 32 * 64; e += 256) {
            int n = e >> 6, k = e & 63;
            W2t[e] = __float2half(W2[k * 32 + n]);
        }
        return;
    }
    __shared__ int lh[1024];
    for (int i = threadIdx.x; i < NB; i += 256) lh[i] = 0;
    __syncthreads();
    int start = b * CH, end = min(E, start + CH);
    for (int e0 = start + threadIdx.x * 4; e0 < end; e0 += 1024) {
        if (e0 + 4 <= end) {
            int4 d4 = *reinterpret_cast<const int4*>(dst + e0);
            atomicAdd(&lh[d4.x >> BSH], 1);
            atomicAdd(&lh[d4.y >> BSH], 1);
            atomicAdd(&lh[d4.z >> BSH], 1);
            atomicAdd(&lh[d4.w >> BSH], 1);
        } else {
            for (int e = e0; e < end; ++e) atomicAdd(&lh[dst[e] >> BSH], 1);
        }
    }
    __syncthreads();
    for (int k = threadIdx.x; k < NB; k += 256)
        hist_T[k * NBLK + b] = lh[k];
}

__global__ __launch_bounds__(256) void bucket_scatter_kernel(const int* __restrict__ src,
                                                             const int* __restrict__ dst,
                                                             const int* __restrict__ tmp,
                                                             const int* __restrict__ bscan,
                                                             int* __restrict__ buck,
                                                             int E, int CH, int NB) {
    __shared__ int cur[1024];
    int b = blockIdx.x;
    for (int i = threadIdx.x; i < NB; i += 256) {
        int idx = i * NBLK + b;
        cur[i] = tmp[idx] + bscan[idx >> 10];
    }
    __syncthreads();
    int start = b * CH, end = min(E, start + CH);
    for (int e0 = start + threadIdx.x * 4; e0 < end; e0 += 1024) {
        if (e0 + 4 <= end) {
            int4 s4 = *reinterpret_cast<const int4*>(src + e0);
            int4 d4 = *reinterpret_cast<const int4*>(dst + e0);
            int p0 = atomicAdd(&cur[d4.x >> BSH], 1);
            buck[p0] = (s4.x << BSH) | (d4.x & (BNODES - 1));
            int p1 = atomicAdd(&cur[d4.y >> BSH], 1);
            buck[p1] = (s4.y << BSH) | (d4.y & (BNODES - 1));
            int p2 = atomicAdd(&cur[d4.z >> BSH], 1);
            buck[p2] = (s4.z << BSH) | (d4.z & (BNODES - 1));
            int p3 = atomicAdd(&cur[d4.w >> BSH], 1);
            buck[p3] = (s4.w << BSH) | (d4.w & (BNODES - 1));
        } else {
            for (int e = e0; e < end; ++e) {
                int d = dst[e];
                int pos = atomicAdd(&cur[d >> BSH], 1);
                buck[pos] = (src[e] << BSH) | (d & (BNODES - 1));
            }
        }
    }
}

// Fused: per-bucket degree count -> LDS exclusive scan -> row_off/deg/dinv
// -> in-bucket CSR fill (second buck read is L2-hot). Replaces deg+scan2+fill.
__global__ __launch_bounds__(256) void bucket_deg_fill_kernel(const int* __restrict__ buck,
                                                              const int* __restrict__ tmp,
                                                              const int* __restrict__ bscan,
                                                              int* __restrict__ deg,
                                                              float* __restrict__ dinv,
                                                              int* __restrict__ row_off,
                                                              int* __restrict__ csr,
                                                              int E, int N, int NB) {
    __shared__ int cnt[BNODES];
    __shared__ int sc[BNODES];
    __shared__ int lrow[BNODES];
    __shared__ int lcur[BNODES];
    int k = blockIdx.x;
    int tid = threadIdx.x;
    if (tid < BNODES) { cnt[tid] = 0; lcur[tid] = 0; }
    __syncthreads();
    int i0 = k * NBLK;
    int bs = tmp[i0] + bscan[i0 >> 10];
    int be = E;
    if (k + 1 < NB) {
        int i1 = (k + 1) * NBLK;
        be = tmp[i1] + bscan[i1 >> 10];
    }
    for (int e = bs + tid; e < be; e += 256)
        atomicAdd(&cnt[buck[e] & (BNODES - 1)], 1);
    __syncthreads();
    if (tid < BNODES) sc[tid] = cnt[tid];
    __syncthreads();
    for (int ofs = 1; ofs < BNODES; ofs <<= 1) {
        int v = (tid >= ofs && tid < BNODES) ? sc[tid - ofs] : 0;
        __syncthreads();
        if (tid < BNODES) sc[tid] += v;
        __syncthreads();
    }
    if (tid < BNODES) {
        int excl = sc[tid] - cnt[tid];
        lrow[tid] = bs + excl;  // == global exclusive scan of deg at this node
        int i = (k << BSH) + tid;
        if (i < N) {
            deg[i] = cnt[tid];
            dinv[i] = rsqrtf((float)(cnt[tid] + 1));  // +1 self loop
            row_off[i] = bs + excl;
        }
    }
    __syncthreads();
    for (int e = bs + tid; e < be; e += 256) {
        int p = buck[e];
        int li = p & (BNODES - 1);
        int pos = lrow[li] + atomicAdd(&lcur[li], 1);
        csr[pos] = p >> BSH;
    }
}

// ---------------- MFMA GEMM: C = half((A @ B) * dinv[row]) ----------------

__device__ __forceinline__ int swz(int p, int r) { return (p ^ ((r >> 1) & 3)) << 4; }

template <bool AF32, int K, int BN>
__global__ __launch_bounds__(256) void gemm_mfma_kernel(const void* __restrict__ Aptr,
                                                        const __half* __restrict__ Bt,
                                                        const float* __restrict__ dinv,
                                                        __half* __restrict__ C,
                                                        int M) {
    constexpr int NT = BN / 16;
    __shared__ half8 Ash[64 * 4];   // 64 rows x 64B
    __shared__ half8 Bsh[BN * 4];   // BN cols x 64B
    char* Ab = (char*)Ash;
    char* Bb = (char*)Bsh;
    int tid = threadIdx.x;
    int w = tid >> 6;
    int l = tid & 63;
    int row0 = blockIdx.x * 64;
    int sr = tid >> 2, sp = tid & 3;   // staging row / k-plane
    int fr = l & 15, fp = l >> 4;      // fragment row(col) / k-plane
    int arow = w * 16 + fr;
    int a_off = arow * 64 + swz(fp, arow);

    floatx4 acc[NT];
#pragma unroll
    for (int c = 0; c < NT; ++c) acc[c] = (floatx4){0.f, 0.f, 0.f, 0.f};

    for (int k0 = 0; k0 < K; k0 += 32) {
        half8 av = {};
        int gr = row0 + sr;
        if (gr < M) {
            if constexpr (AF32) {
                const float* A = (const float*)Aptr;
                float4 f0 = *(const float4*)(A + (size_t)gr * K + k0 + sp * 8);
                float4 f1 = *(const float4*)(A + (size_t)gr * K + k0 + sp * 8 + 4);
                av[0] = (_Float16)f0.x; av[1] = (_Float16)f0.y;
                av[2] = (_Float16)f0.z; av[3] = (_Float16)f0.w;
                av[4] = (_Float16)f1.x; av[5] = (_Float16)f1.y;
                av[6] = (_Float16)f1.z; av[7] = (_Float16)f1.w;
            } else {
                const __half* A = (const __half*)Aptr;
                av = *(const half8*)(A + (size_t)gr * K + k0 + sp * 8);
            }
        }
        *(half8*)(Ab + sr * 64 + swz(sp, sr)) = av;
        if (tid < BN * 4) {
            int n = tid >> 2, p = tid & 3;
            half8 bv = *(const half8*)(Bt + (size_t)n * K + k0 + p * 8);
            *(half8*)(Bb + n * 64 + swz(p, n)) = bv;
        }
        __syncthreads();
        half8 a = *(const half8*)(Ab + a_off);
#pragma unroll
        for (int c = 0; c < NT; ++c) {
            int col = c * 16 + fr;
            half8 b = *(const half8*)(Bb + col * 64 + swz(fp, col));
            acc[c] = __builtin_amdgcn_mfma_f32_16x16x32_f16(a, b, acc[c], 0, 0, 0);
        }
        __syncthreads();
    }
#pragma unroll
    for (int i = 0; i < 4; ++i) {
        int r = row0 + w * 16 + fp * 4 + i;
        if (r < M) {
            float dn = dinv[r];
#pragma unroll
            for (int c = 0; c < NT; ++c)
                C[(size_t)r * BN + c * 16 + fr] = __float2half(acc[c][i] * dn);
        }
    }
}

// ---------------- gather helpers ----------------

__device__ __forceinline__ void acc_row16(const __half* __restrict__ base, float* a) {
    uint4 raw = *reinterpret_cast<const uint4*>(base);
    float2 f0 = __half22float2(*reinterpret_cast<const __half2*>(&raw.x));
    float2 f1 = __half22float2(*reinterpret_cast<const __half2*>(&raw.y));
    float2 f2 = __half22float2(*reinterpret_cast<const __half2*>(&raw.z));
    float2 f3 = __half22float2(*reinterpret_cast<const __half2*>(&raw.w));
    a[0] += f0.x; a[1] += f0.y; a[2] += f1.x; a[3] += f1.y;
    a[4] += f2.x; a[5] += f2.y; a[6] += f3.x; a[7] += f3.y;
}

// packed fp16 accumulate from a preloaded 16B chunk: 4 v_pk_add_f16
__device__ __forceinline__ void acc_pk_raw(uint4 raw, __half2* c2) {
    c2[0] = __hadd2(c2[0], *reinterpret_cast<const __half2*>(&raw.x));
    c2[1] = __hadd2(c2[1], *reinterpret_cast<const __half2*>(&raw.y));
    c2[2] = __hadd2(c2[2], *reinterpret_cast<const __half2*>(&raw.z));
    c2[3] = __hadd2(c2[3], *reinterpret_cast<const __half2*>(&raw.w));
}

__device__ __forceinline__ void flush_pk(__half2* c2, float* a) {
#pragma unroll
    for (int j = 0; j < 4; ++j) {
        float2 f = __half22float2(c2[j]);
        a[2 * j] += f.x;
        a[2 * j + 1] += f.y;
        c2[j] = __float2half2_rn(0.f);
    }
}

// ---------------- Aggregation layer 1: wave per node (pure, no fusion) ----------------
// 8 edge-groups x 8 lanes x 16B; 32-edge superblock = 4 gathers in flight,
// 16-edge remainder = 2-deep. fp16 chains <=4 adds then flush. h1 out fp16.

__global__ __launch_bounds__(256) void agg1_kernel(const __half* __restrict__ g1,
                                                   const int* __restrict__ row_off,
                                                   const int* __restrict__ deg,
                                                   const int* __restrict__ csr,
                                                   const float* __restrict__ dinv,
                                                   const float* __restrict__ b1,
                                                   __half* __restrict__ h1, int n) {
    int node = (blockIdx.x * 256 + threadIdx.x) >> 6;
    int lane = threadIdx.x & 63;
    int g = lane >> 3;        // edge group 0..7
    int f8 = lane & 7;        // 16B feature chunk 0..7
    if (node >= n) return;
    int start = row_off[node];
    int end = start + deg[node];
    float a[8];
#pragma unroll
    for (int j = 0; j < 8; ++j) a[j] = 0.f;
    if (g == 0)  // self loop counted once (f32 path)
        acc_row16(g1 + ((size_t)node << 6) + f8 * 8, a);
    __half2 c2[4];
#pragma unroll
    for (int j = 0; j < 4; ++j) c2[j] = __float2half2_rn(0.f);
    int e = start;
    for (; e + 32 <= end; e += 32) {  // 4 independent gathers in flight
        int i0 = csr[e + g];
        int i1 = csr[e + 8 + g];
        int i2 = csr[e + 16 + g];
        int i3 = csr[e + 24 + g];
        uint4 r0 = *reinterpret_cast<const uint4*>(g1 + ((size_t)i0 << 6) + f8 * 8);
        uint4 r1 = *reinterpret_cast<const uint4*>(g1 + ((size_t)i1 << 6) + f8 * 8);
        uint4 r2 = *reinterpret_cast<const uint4*>(g1 + ((size_t)i2 << 6) + f8 * 8);
        uint4 r3 = *reinterpret_cast<const uint4*>(g1 + ((size_t)i3 << 6) + f8 * 8);
        acc_pk_raw(r0, c2);
        acc_pk_raw(r1, c2);
        acc_pk_raw(r2, c2);
        acc_pk_raw(r3, c2);
        flush_pk(c2, a);  // <=4 fp16 adds per chain
    }
    if (e + 16 <= end) {  // 2-deep remainder
        int i0 = csr[e + g];
        int i1 = csr[e + 8 + g];
        uint4 r0 = *reinterpret_cast<const uint4*>(g1 + ((size_t)i0 << 6) + f8 * 8);
        uint4 r1 = *reinterpret_cast<const uint4*>(g1 + ((size_t)i1 << 6) + f8 * 8);
        acc_pk_raw(r0, c2);
        acc_pk_raw(r1, c2);
        e += 16;
    }
    if (e + 8 <= end) {
        int s = csr[e + g];
        uint4 r = *reinterpret_cast<const uint4*>(g1 + ((size_t)s << 6) + f8 * 8);
        acc_pk_raw(r, c2);
        e += 8;
    }
    if (e + g < end) {
        int s = csr[e + g];
        uint4 r = *reinterpret_cast<const uint4*>(g1 + ((size_t)s << 6) + f8 * 8);
        acc_pk_raw(r, c2);
    }
    flush_pk(c2, a);
    // fold 8 edge groups
#pragma unroll
    for (int j = 0; j < 8; ++j) a[j] += __shfl_xor(a[j], 8);
#pragma unroll
    for (int j = 0; j < 8; ++j) a[j] += __shfl_xor(a[j], 16);
#pragma unroll
    for (int j = 0; j < 8; ++j) a[j] += __shfl_xor(a[j], 32);
    if (g == 0) {
        float dn = dinv[node];
        float4 bl = *reinterpret_cast<const float4*>(b1 + f8 * 8);
        float4 bh = *reinterpret_cast<const float4*>(b1 + f8 * 8 + 4);
        __half hh[8];
        hh[0] = __float2half(fmaxf(a[0] * dn + bl.x, 0.f));
        hh[1] = __float2half(fmaxf(a[1] * dn + bl.y, 0.f));
        hh[2] = __float2half(fmaxf(a[2] * dn + bl.z, 0.f));
        hh[3] = __float2half(fmaxf(a[3] * dn + bl.w, 0.f));
        hh[4] = __float2half(fmaxf(a[4] * dn + bh.x, 0.f));
        hh[5] = __float2half(fmaxf(a[5] * dn + bh.y, 0.f));
        hh[6] = __float2half(fmaxf(a[6] * dn + bh.z, 0.f));
        hh[7] = __float2half(fmaxf(a[7] * dn + bh.w, 0.f));
        *reinterpret_cast<uint4*>(h1 + ((size_t)node << 6) + f8 * 8) =
            *reinterpret_cast<const uint4*>(hh);
    }
}

// ---------------- Aggregation layer 2 + pooling: HALF-wave per node ----------------
// 32 lanes/node = 8 edge-groups x 4 lanes x 16B; 32-edge superblock = 4-deep.

__global__ __launch_bounds__(256) void agg2_pool_kernel(const __half* __restrict__ g2,
                                                        const int* __restrict__ row_off,
                                                        const int* __restrict__ deg,
                                                        const int* __restrict__ csr,
                                                        const float* __restrict__ dinv,
                                                        const float* __restrict__ b2,
                                                        float* __restrict__ partials,
                                                        int nblocks, int n) {
    int tid = threadIdx.x;
    int half = tid >> 5;            // half-wave 0..7 in block
    int node = blockIdx.x * 8 + half;
    int l32 = tid & 31;
    int g = (l32 >> 2);             // edge group 0..7
    int f4 = l32 & 3;               // 16B feature chunk 0..3
    float a[8];
#pragma unroll
    for (int j = 0; j < 8; ++j) a[j] = 0.f;
    if (node < n) {
        int start = row_off[node];
        int end = start + deg[node];
        if (g == 0)
            acc_row16(g2 + ((size_t)node << 5) + f4 * 8, a);
        __half2 c2[4];
#pragma unroll
        for (int j = 0; j < 4; ++j) c2[j] = __float2half2_rn(0.f);
        int e = start;
        for (; e + 32 <= end; e += 32) {  // 4-deep
            int i0 = csr[e + g];
            int i1 = csr[e + 8 + g];
            int i2 = csr[e + 16 + g];
            int i3 = csr[e + 24 + g];
            uint4 r0 = *reinterpret_cast<const uint4*>(g2 + ((size_t)i0 << 5) + f4 * 8);
            uint4 r1 = *reinterpret_cast<const uint4*>(g2 + ((size_t)i1 << 5) + f4 * 8);
            uint4 r2 = *reinterpret_cast<const uint4*>(g2 + ((size_t)i2 << 5) + f4 * 8);
            uint4 r3 = *reinterpret_cast<const uint4*>(g2 + ((size_t)i3 << 5) + f4 * 8);
            acc_pk_raw(r0, c2);
            acc_pk_raw(r1, c2);
            acc_pk_raw(r2, c2);
            acc_pk_raw(r3, c2);
            flush_pk(c2, a);
        }
        if (e + 16 <= end) {  // 2-deep remainder
            int i0 = csr[e + g];
            int i1 = csr[e + 8 + g];
            uint4 r0 = *reinterpret_cast<const uint4*>(g2 + ((size_t)i0 << 5) + f4 * 8);
            uint4 r1 = *reinterpret_cast<const uint4*>(g2 + ((size_t)i1 << 5) + f4 * 8);
            acc_pk_raw(r0, c2);
            acc_pk_raw(r1, c2);
            e += 16;
        }
        if (e + 8 <= end) {
            int s = csr[e + g];
            uint4 r = *reinterpret_cast<const uint4*>(g2 + ((size_t)s << 5) + f4 * 8);
            acc_pk_raw(r, c2);
            e += 8;
        }
        if (e + g < end) {
            int s = csr[e + g];
            uint4 r = *reinterpret_cast<const uint4*>(g2 + ((size_t)s << 5) + f4 * 8);
            acc_pk_raw(r, c2);
        }
        flush_pk(c2, a);
        // fold 8 edge groups within the half-wave
#pragma unroll
        for (int j = 0; j < 8; ++j) a[j] += __shfl_xor(a[j], 4);
#pragma unroll
        for (int j = 0; j < 8; ++j) a[j] += __shfl_xor(a[j], 8);
#pragma unroll
        for (int j = 0; j < 8; ++j) a[j] += __shfl_xor(a[j], 16);
    }
    __shared__ float sdata[8][32];
    if (g == 0) {  // lanes l32 0..3 hold chunks f4
        float relu[8];
        if (node < n) {
            float dn = dinv[node];
#pragma unroll
            for (int j = 0; j < 8; ++j)
                relu[j] = fmaxf(a[j] * dn + b2[f4 * 8 + j], 0.f);
        } else {
#pragma unroll
            for (int j = 0; j < 8; ++j) relu[j] = 0.f;
        }
#pragma unroll
        for (int j = 0; j < 8; ++j) sdata[half][f4 * 8 + j] = relu[j];
    }
    __syncthreads();
    if (tid < 32) {
        float s = 0.f;
#pragma unroll
        for (int r = 0; r < 8; ++r) s += sdata[r][tid];
        partials[tid * nblocks + blockIdx.x] = s;
    }
}

// 32 blocks, one per feature; fused FC: atomicAdd into pre-zeroed out[0].
__global__ __launch_bounds__(256) void reduce_fc_kernel(const float* __restrict__ partials,
                                                        int nblocks,
                                                        const float* __restrict__ fcw,
                                                        const float* __restrict__ fcb,
                                                        float* __restrict__ out, int n) {
    int f = blockIdx.x;
    const float* col = partials + (size_t)f * nblocks;
    float s = 0.f;
    for (int i = threadIdx.x; i < nblocks; i += 256) s += col[i];
    __shared__ float red[256];
    red[threadIdx.x] = s;
    __syncthreads();
    for (int ofs = 128; ofs > 0; ofs >>= 1) {
        if (threadIdx.x < ofs) red[threadIdx.x] += red[threadIdx.x + ofs];
        __syncthreads();
    }
    if (threadIdx.x == 0) {
        float v = (float)((double)red[0] / (double)n * (double)fcw[f]);
        if (f == 0) v += fcb[0];
        atomicAdd(out, v);
    }
}

// ---------------- launch ----------------

extern "C" void kernel_launch(void* const* d_in, const int* in_sizes, int n_in,
                              void* d_out, int out_size, void* d_ws, size_t ws_size,
                              hipStream_t stream) {
    const float* x   = (const float*)d_in[0];
    const int*   ei  = (const int*)d_in[1];
    const float* W1  = (const float*)d_in[2];
    const float* b1  = (const float*)d_in[3];
    const float* W2  = (const float*)d_in[4];
    const float* b2  = (const float*)d_in[5];
    const float* fcw = (const float*)d_in[6];
    const float* fcb = (const float*)d_in[7];
    float* out = (float*)d_out;

    const int N = in_sizes[0] / 256;  // 100000
    const int E = in_sizes[1] / 2;    // 3200000
    const int* src = ei;
    const int* dst = ei + E;

    const int NB = (N + BNODES - 1) >> BSH;            // 782 buckets
    const int SC = NB * NBLK;                          // hist entries
    const int CH = (((E + NBLK - 1) / NBLK) + 3) & ~3; // edges/block, x4 aligned
    const int nb2 = (N + 7) / 8;                       // agg2 blocks (8 nodes)

    char* ws = (char*)d_ws;
    size_t off = 0;
    auto alloc = [&](size_t bytes) -> void* {
        void* p = ws + off;
        off = (off + bytes + 255) & ~(size_t)255;
        return p;
    };
    int*   tmp      = (int*)alloc((size_t)SC * 4);   // scan1 (bucket offsets)
    int*   bsums    = (int*)alloc(2048);
    int*   bscan    = (int*)alloc(2048);
    int*   row_off  = (int*)alloc((size_t)N * 4);
    int*   deg      = (int*)alloc((size_t)N * 4);
    float* dinv     = (float*)alloc((size_t)N * 4);
    int*   csr      = (int*)alloc((size_t)E * 4);
    __half* W1t     = (__half*)alloc((size_t)64 * 256 * 2);
    __half* W2t     = (__half*)alloc((size_t)32 * 64 * 2);
    // region P: buck (E int) aliases g1 (N*F1 halves) — buck dead before gemm1
    size_t szP = (size_t)E * 4;
    size_t szG1 = (size_t)N * F1 * 2;
    void* P = alloc(szP > szG1 ? szP : szG1);
    int*    buck = (int*)P;
    __half* g1   = (__half*)P;
    int*   hist_T   = (int*)alloc((size_t)SC * 4);
    __half* h1      = (__half*)alloc((size_t)N * F1 * 2);
    __half* g2      = (__half*)alloc((size_t)N * F2 * 2);
    float* partials = (float*)alloc((size_t)F2 * nb2 * 4);

    hipMemsetAsync(out, 0, sizeof(float), stream);

    // ---- CSR build via counting sort + weight prep ----
    bucket_hist_prep_kernel<<<NBLK + 1, 256, 0, stream>>>(dst, hist_T, W1, W2, W1t, W2t, E, CH, NB);
    int nbS = (SC + 1023) / 1024;  // 391
    scan_blocks_kernel<<<nbS, 256, 0, stream>>>(hist_T, tmp, bsums, SC);
    scan_sums_kernel<<<1, 512, 0, stream>>>(bsums, bscan, nbS);
    bucket_scatter_kernel<<<NBLK, 256, 0, stream>>>(src, dst, tmp, bscan, buck, E, CH, NB);
    bucket_deg_fill_kernel<<<NB, 256, 0, stream>>>(buck, tmp, bscan, deg, dinv, row_off, csr, E, N, NB);

    int nbG = (N + 63) / 64;  // 1563
    // ---- layer 1 ----
    gemm_mfma_kernel<true, 256, 64><<<nbG, 256, 0, stream>>>(x, W1t, dinv, g1, N);
    agg1_kernel<<<(N + 3) / 4, 256, 0, stream>>>(g1, row_off, deg, csr, dinv, b1, h1, N);

    // ---- layer 2 ----
    gemm_mfma_kernel<false, 64, 32><<<nbG, 256, 0, stream>>>(h1, W2t, dinv, g2, N);
    agg2_pool_kernel<<<nb2, 256, 0, stream>>>(g2, row_off, deg, csr, dinv, b2, partials, nb2, N);

    reduce_fc_kernel<<<F2, 256, 0, stream>>>(partials, nb2, fcw, fcb, out, N);
}

// Round 14
// 211.348 us; speedup vs baseline: 1.3472x; 1.0217x over previous
//
#include <hip/hip_runtime.h>
#include <hip/hip_fp16.h>

#ifndef F1
#define F1 64
#define F2 32
#endif

#define NBLK 512     // blocks for bucket hist/scatter passes
#define BSH  7       // bucket = dst >> 7  (128 nodes per bucket)
#define BNODES 128

typedef _Float16 half8 __attribute__((ext_vector_type(8)));
typedef float floatx4 __attribute__((ext_vector_type(4)));

// ---------------- scans ----------------
__global__ __launch_bounds__(256) void scan_blocks_kernel(const int* __restrict__ in,
                                                          int* __restrict__ tmp,
                                                          int* __restrict__ blk_sums, int n) {
    __shared__ int sdata[256];
    int t = threadIdx.x;
    int base = blockIdx.x * 1024 + t * 4;
    int v[4];
#pragma unroll
    for (int j = 0; j < 4; ++j) v[j] = (base + j < n) ? in[base + j] : 0;
    int mysum = v[0] + v[1] + v[2] + v[3];
    sdata[t] = mysum;
    __syncthreads();
    for (int ofs = 1; ofs < 256; ofs <<= 1) {
        int val = (t >= ofs) ? sdata[t - ofs] : 0;
        __syncthreads();
        sdata[t] += val;
        __syncthreads();
    }
    int incl = sdata[t];
    int excl = incl - mysum;
    if (t == 255) blk_sums[blockIdx.x] = incl;
    int run = excl;
#pragma unroll
    for (int j = 0; j < 4; ++j) {
        if (base + j < n) tmp[base + j] = run;
        run += v[j];
    }
}

__global__ __launch_bounds__(512) void scan_sums_kernel(const int* __restrict__ blk_sums,
                                                        int* __restrict__ blk_scanned, int nb) {
    __shared__ int sdata[512];
    int t = threadIdx.x;
    int mine = (t < nb) ? blk_sums[t] : 0;
    sdata[t] = mine;
    __syncthreads();
    for (int ofs = 1; ofs < 512; ofs <<= 1) {
        int val = (t >= ofs) ? sdata[t - ofs] : 0;
        __syncthreads();
        sdata[t] += val;
        __syncthreads();
    }
    blk_scanned[t] = sdata[t] - mine;  // exclusive
}

// ---------------- bucket passes (counting sort by dst>>BSH) ----------------

__global__ __launch_bounds__(256) void bucket_hist_prep_kernel(const int* __restrict__ dst,
                                                               int* __restrict__ hist_T,
                                                               const float* __restrict__ W1,
                                                               const float* __restrict__ W2,
                                                               __half* __restrict__ W1t,
                                                               __half* __restrict__ W2t,
                                                               float* __restrict__ out,
                                                               int E, int CH, int NB) {
    int b = blockIdx.x;
    if (b == NBLK) {  // weight prep: Wt[n][k] = half(W[k][n]); also zero out[0]
        if (threadIdx.x == 0) out[0] = 0.f;  // replaces pathological hipMemsetAsync
        for (int e = threadIdx.x; e < 64 * 256; e += 256) {
            int n = e >> 8, k = e & 255;
            W1t[e] = __float2half(W1[k * 64 + n]);
        }
        for (int e = threadIdx.x; e < 32 * 64; e += 256) {
            int n = e >> 6, k = e & 63;
            W2t[e] = __float2half(W2[k * 32 + n]);
        }
        return;
    }
    __shared__ int lh[1024];
    for (int i = threadIdx.x; i < NB; i += 256) lh[i] = 0;
    __syncthreads();
    int start = b * CH, end = min(E, start + CH);
    for (int e0 = start + threadIdx.x * 4; e0 < end; e0 += 1024) {
        if (e0 + 4 <= end) {
            int4 d4 = *reinterpret_cast<const int4*>(dst + e0);
            atomicAdd(&lh[d4.x >> BSH], 1);
            atomicAdd(&lh[d4.y >> BSH], 1);
            atomicAdd(&lh[d4.z >> BSH], 1);
            atomicAdd(&lh[d4.w >> BSH], 1);
        } else {
            for (int e = e0; e < end; ++e) atomicAdd(&lh[dst[e] >> BSH], 1);
        }
    }
    __syncthreads();
    for (int k = threadIdx.x; k < NB; k += 256)
        hist_T[k * NBLK + b] = lh[k];
}

__global__ __launch_bounds__(256) void bucket_scatter_kernel(const int* __restrict__ src,
                                                             const int* __restrict__ dst,
                                                             const int* __restrict__ tmp,
                                                             const int* __restrict__ bscan,
                                                             int* __restrict__ buck,
                                                             int E, int CH, int NB) {
    __shared__ int cur[1024];
    int b = blockIdx.x;
    for (int i = threadIdx.x; i < NB; i += 256) {
        int idx = i * NBLK + b;
        cur[i] = tmp[idx] + bscan[idx >> 10];
    }
    __syncthreads();
    int start = b * CH, end = min(E, start + CH);
    for (int e0 = start + threadIdx.x * 4; e0 < end; e0 += 1024) {
        if (e0 + 4 <= end) {
            int4 s4 = *reinterpret_cast<const int4*>(src + e0);
            int4 d4 = *reinterpret_cast<const int4*>(dst + e0);
            int p0 = atomicAdd(&cur[d4.x >> BSH], 1);
            buck[p0] = (s4.x << BSH) | (d4.x & (BNODES - 1));
            int p1 = atomicAdd(&cur[d4.y >> BSH], 1);
            buck[p1] = (s4.y << BSH) | (d4.y & (BNODES - 1));
            int p2 = atomicAdd(&cur[d4.z >> BSH], 1);
            buck[p2] = (s4.z << BSH) | (d4.z & (BNODES - 1));
            int p3 = atomicAdd(&cur[d4.w >> BSH], 1);
            buck[p3] = (s4.w << BSH) | (d4.w & (BNODES - 1));
        } else {
            for (int e = e0; e < end; ++e) {
                int d = dst[e];
                int pos = atomicAdd(&cur[d >> BSH], 1);
                buck[pos] = (src[e] << BSH) | (d & (BNODES - 1));
            }
        }
    }
}

// Fused: per-bucket degree count -> LDS exclusive scan -> row_off/deg/dinv
// -> in-bucket CSR fill (second buck read is L2-hot).
__global__ __launch_bounds__(256) void bucket_deg_fill_kernel(const int* __restrict__ buck,
                                                              const int* __restrict__ tmp,
                                                              const int* __restrict__ bscan,
                                                              int* __restrict__ deg,
                                                              float* __restrict__ dinv,
                                                              int* __restrict__ row_off,
                                                              int* __restrict__ csr,
                                                              int E, int N, int NB) {
    __shared__ int cnt[BNODES];
    __shared__ int sc[BNODES];
    __shared__ int lrow[BNODES];
    __shared__ int lcur[BNODES];
    int k = blockIdx.x;
    int tid = threadIdx.x;
    if (tid < BNODES) { cnt[tid] = 0; lcur[tid] = 0; }
    __syncthreads();
    int i0 = k * NBLK;
    int bs = tmp[i0] + bscan[i0 >> 10];
    int be = E;
    if (k + 1 < NB) {
        int i1 = (k + 1) * NBLK;
        be = tmp[i1] + bscan[i1 >> 10];
    }
    for (int e = bs + tid; e < be; e += 256)
        atomicAdd(&cnt[buck[e] & (BNODES - 1)], 1);
    __syncthreads();
    if (tid < BNODES) sc[tid] = cnt[tid];
    __syncthreads();
    for (int ofs = 1; ofs < BNODES; ofs <<= 1) {
        int v = (tid >= ofs && tid < BNODES) ? sc[tid - ofs] : 0;
        __syncthreads();
        if (tid < BNODES) sc[tid] += v;
        __syncthreads();
    }
    if (tid < BNODES) {
        int excl = sc[tid] - cnt[tid];
        lrow[tid] = bs + excl;  // == global exclusive scan of deg at this node
        int i = (k << BSH) + tid;
        if (i < N) {
            deg[i] = cnt[tid];
            dinv[i] = rsqrtf((float)(cnt[tid] + 1));  // +1 self loop
            row_off[i] = bs + excl;
        }
    }
    __syncthreads();
    for (int e = bs + tid; e < be; e += 256) {
        int p = buck[e];
        int li = p & (BNODES - 1);
        int pos = lrow[li] + atomicAdd(&lcur[li], 1);
        csr[pos] = p >> BSH;
    }
}

// ---------------- MFMA GEMM: C = half((A @ B) * dinv[row]) ----------------

__device__ __forceinline__ int swz(int p, int r) { return (p ^ ((r >> 1) & 3)) << 4; }

template <bool AF32, int K, int BN>
__global__ __launch_bounds__(256) void gemm_mfma_kernel(const void* __restrict__ Aptr,
                                                        const __half* __restrict__ Bt,
                                                        const float* __restrict__ dinv,
                                                        __half* __restrict__ C,
                                                        int M) {
    constexpr int NT = BN / 16;
    __shared__ half8 Ash[64 * 4];   // 64 rows x 64B
    __shared__ half8 Bsh[BN * 4];   // BN cols x 64B
    char* Ab = (char*)Ash;
    char* Bb = (char*)Bsh;
    int tid = threadIdx.x;
    int w = tid >> 6;
    int l = tid & 63;
    int row0 = blockIdx.x * 64;
    int sr = tid >> 2, sp = tid & 3;   // staging row / k-plane
    int fr = l & 15, fp = l >> 4;      // fragment row(col) / k-plane
    int arow = w * 16 + fr;
    int a_off = arow * 64 + swz(fp, arow);

    floatx4 acc[NT];
#pragma unroll
    for (int c = 0; c < NT; ++c) acc[c] = (floatx4){0.f, 0.f, 0.f, 0.f};

    for (int k0 = 0; k0 < K; k0 += 32) {
        half8 av = {};
        int gr = row0 + sr;
        if (gr < M) {
            if constexpr (AF32) {
                const float* A = (const float*)Aptr;
                float4 f0 = *(const float4*)(A + (size_t)gr * K + k0 + sp * 8);
                float4 f1 = *(const float4*)(A + (size_t)gr * K + k0 + sp * 8 + 4);
                av[0] = (_Float16)f0.x; av[1] = (_Float16)f0.y;
                av[2] = (_Float16)f0.z; av[3] = (_Float16)f0.w;
                av[4] = (_Float16)f1.x; av[5] = (_Float16)f1.y;
                av[6] = (_Float16)f1.z; av[7] = (_Float16)f1.w;
            } else {
                const __half* A = (const __half*)Aptr;
                av = *(const half8*)(A + (size_t)gr * K + k0 + sp * 8);
            }
        }
        *(half8*)(Ab + sr * 64 + swz(sp, sr)) = av;
        if (tid < BN * 4) {
            int n = tid >> 2, p = tid & 3;
            half8 bv = *(const half8*)(Bt + (size_t)n * K + k0 + p * 8);
            *(half8*)(Bb + n * 64 + swz(p, n)) = bv;
        }
        __syncthreads();
        half8 a = *(const half8*)(Ab + a_off);
#pragma unroll
        for (int c = 0; c < NT; ++c) {
            int col = c * 16 + fr;
            half8 b = *(const half8*)(Bb + col * 64 + swz(fp, col));
            acc[c] = __builtin_amdgcn_mfma_f32_16x16x32_f16(a, b, acc[c], 0, 0, 0);
        }
        __syncthreads();
    }
#pragma unroll
    for (int i = 0; i < 4; ++i) {
        int r = row0 + w * 16 + fp * 4 + i;
        if (r < M) {
            float dn = dinv[r];
#pragma unroll
            for (int c = 0; c < NT; ++c)
                C[(size_t)r * BN + c * 16 + fr] = __float2half(acc[c][i] * dn);
        }
    }
}

// ---------------- gather helpers ----------------

__device__ __forceinline__ void acc_row16(const __half* __restrict__ base, float* a) {
    uint4 raw = *reinterpret_cast<const uint4*>(base);
    float2 f0 = __half22float2(*reinterpret_cast<const __half2*>(&raw.x));
    float2 f1 = __half22float2(*reinterpret_cast<const __half2*>(&raw.y));
    float2 f2 = __half22float2(*reinterpret_cast<const __half2*>(&raw.z));
    float2 f3 = __half22float2(*reinterpret_cast<const __half2*>(&raw.w));
    a[0] += f0.x; a[1] += f0.y; a[2] += f1.x; a[3] += f1.y;
    a[4] += f2.x; a[5] += f2.y; a[6] += f3.x; a[7] += f3.y;
}

// packed fp16 accumulate from a preloaded 16B chunk: 4 v_pk_add_f16
__device__ __forceinline__ void acc_pk_raw(uint4 raw, __half2* c2) {
    c2[0] = __hadd2(c2[0], *reinterpret_cast<const __half2*>(&raw.x));
    c2[1] = __hadd2(c2[1], *reinterpret_cast<const __half2*>(&raw.y));
    c2[2] = __hadd2(c2[2], *reinterpret_cast<const __half2*>(&raw.z));
    c2[3] = __hadd2(c2[3], *reinterpret_cast<const __half2*>(&raw.w));
}

__device__ __forceinline__ void flush_pk(__half2* c2, float* a) {
#pragma unroll
    for (int j = 0; j < 4; ++j) {
        float2 f = __half22float2(c2[j]);
        a[2 * j] += f.x;
        a[2 * j + 1] += f.y;
        c2[j] = __float2half2_rn(0.f);
    }
}

// ---------------- Aggregation layer 1: wave per node ----------------
// 8 edge-groups x 8 lanes x 16B; 32-edge superblock = 4 gathers in flight,
// 16-edge remainder = 2-deep. fp16 chains <=4 adds then flush. h1 out fp16.

__global__ __launch_bounds__(256) void agg1_kernel(const __half* __restrict__ g1,
                                                   const int* __restrict__ row_off,
                                                   const int* __restrict__ deg,
                                                   const int* __restrict__ csr,
                                                   const float* __restrict__ dinv,
                                                   const float* __restrict__ b1,
                                                   __half* __restrict__ h1, int n) {
    int node = (blockIdx.x * 256 + threadIdx.x) >> 6;
    int lane = threadIdx.x & 63;
    int g = lane >> 3;        // edge group 0..7
    int f8 = lane & 7;        // 16B feature chunk 0..7
    if (node >= n) return;
    int start = row_off[node];
    int end = start + deg[node];
    float a[8];
#pragma unroll
    for (int j = 0; j < 8; ++j) a[j] = 0.f;
    if (g == 0)  // self loop counted once (f32 path)
        acc_row16(g1 + ((size_t)node << 6) + f8 * 8, a);
    __half2 c2[4];
#pragma unroll
    for (int j = 0; j < 4; ++j) c2[j] = __float2half2_rn(0.f);
    int e = start;
    for (; e + 32 <= end; e += 32) {  // 4 independent gathers in flight
        int i0 = csr[e + g];
        int i1 = csr[e + 8 + g];
        int i2 = csr[e + 16 + g];
        int i3 = csr[e + 24 + g];
        uint4 r0 = *reinterpret_cast<const uint4*>(g1 + ((size_t)i0 << 6) + f8 * 8);
        uint4 r1 = *reinterpret_cast<const uint4*>(g1 + ((size_t)i1 << 6) + f8 * 8);
        uint4 r2 = *reinterpret_cast<const uint4*>(g1 + ((size_t)i2 << 6) + f8 * 8);
        uint4 r3 = *reinterpret_cast<const uint4*>(g1 + ((size_t)i3 << 6) + f8 * 8);
        acc_pk_raw(r0, c2);
        acc_pk_raw(r1, c2);
        acc_pk_raw(r2, c2);
        acc_pk_raw(r3, c2);
        flush_pk(c2, a);  // <=4 fp16 adds per chain
    }
    if (e + 16 <= end) {  // 2-deep remainder
        int i0 = csr[e + g];
        int i1 = csr[e + 8 + g];
        uint4 r0 = *reinterpret_cast<const uint4*>(g1 + ((size_t)i0 << 6) + f8 * 8);
        uint4 r1 = *reinterpret_cast<const uint4*>(g1 + ((size_t)i1 << 6) + f8 * 8);
        acc_pk_raw(r0, c2);
        acc_pk_raw(r1, c2);
        e += 16;
    }
    if (e + 8 <= end) {
        int s = csr[e + g];
        uint4 r = *reinterpret_cast<const uint4*>(g1 + ((size_t)s << 6) + f8 * 8);
        acc_pk_raw(r, c2);
        e += 8;
    }
    if (e + g < end) {
        int s = csr[e + g];
        uint4 r = *reinterpret_cast<const uint4*>(g1 + ((size_t)s << 6) + f8 * 8);
        acc_pk_raw(r, c2);
    }
    flush_pk(c2, a);
    // fold 8 edge groups
#pragma unroll
    for (int j = 0; j < 8; ++j) a[j] += __shfl_xor(a[j], 8);
#pragma unroll
    for (int j = 0; j < 8; ++j) a[j] += __shfl_xor(a[j], 16);
#pragma unroll
    for (int j = 0; j < 8; ++j) a[j] += __shfl_xor(a[j], 32);
    if (g == 0) {
        float dn = dinv[node];
        float4 bl = *reinterpret_cast<const float4*>(b1 + f8 * 8);
        float4 bh = *reinterpret_cast<const float4*>(b1 + f8 * 8 + 4);
        __half hh[8];
        hh[0] = __float2half(fmaxf(a[0] * dn + bl.x, 0.f));
        hh[1] = __float2half(fmaxf(a[1] * dn + bl.y, 0.f));
        hh[2] = __float2half(fmaxf(a[2] * dn + bl.z, 0.f));
        hh[3] = __float2half(fmaxf(a[3] * dn + bl.w, 0.f));
        hh[4] = __float2half(fmaxf(a[4] * dn + bh.x, 0.f));
        hh[5] = __float2half(fmaxf(a[5] * dn + bh.y, 0.f));
        hh[6] = __float2half(fmaxf(a[6] * dn + bh.z, 0.f));
        hh[7] = __float2half(fmaxf(a[7] * dn + bh.w, 0.f));
        *reinterpret_cast<uint4*>(h1 + ((size_t)node << 6) + f8 * 8) =
            *reinterpret_cast<const uint4*>(hh);
    }
}

// ---------------- Aggregation layer 2 + pooling: HALF-wave per node ----------------
// 32 lanes/node = 8 edge-groups x 4 lanes x 16B; 32-edge superblock = 4-deep.

__global__ __launch_bounds__(256) void agg2_pool_kernel(const __half* __restrict__ g2,
                                                        const int* __restrict__ row_off,
                                                        const int* __restrict__ deg,
                                                        const int* __restrict__ csr,
                                                        const float* __restrict__ dinv,
                                                        const float* __restrict__ b2,
                                                        float* __restrict__ partials,
                                                        int nblocks, int n) {
    int tid = threadIdx.x;
    int half = tid >> 5;            // half-wave 0..7 in block
    int node = blockIdx.x * 8 + half;
    int l32 = tid & 31;
    int g = (l32 >> 2);             // edge group 0..7
    int f4 = l32 & 3;               // 16B feature chunk 0..3
    float a[8];
#pragma unroll
    for (int j = 0; j < 8; ++j) a[j] = 0.f;
    if (node < n) {
        int start = row_off[node];
        int end = start + deg[node];
        if (g == 0)
            acc_row16(g2 + ((size_t)node << 5) + f4 * 8, a);
        __half2 c2[4];
#pragma unroll
        for (int j = 0; j < 4; ++j) c2[j] = __float2half2_rn(0.f);
        int e = start;
        for (; e + 32 <= end; e += 32) {  // 4-deep
            int i0 = csr[e + g];
            int i1 = csr[e + 8 + g];
            int i2 = csr[e + 16 + g];
            int i3 = csr[e + 24 + g];
            uint4 r0 = *reinterpret_cast<const uint4*>(g2 + ((size_t)i0 << 5) + f4 * 8);
            uint4 r1 = *reinterpret_cast<const uint4*>(g2 + ((size_t)i1 << 5) + f4 * 8);
            uint4 r2 = *reinterpret_cast<const uint4*>(g2 + ((size_t)i2 << 5) + f4 * 8);
            uint4 r3 = *reinterpret_cast<const uint4*>(g2 + ((size_t)i3 << 5) + f4 * 8);
            acc_pk_raw(r0, c2);
            acc_pk_raw(r1, c2);
            acc_pk_raw(r2, c2);
            acc_pk_raw(r3, c2);
            flush_pk(c2, a);
        }
        if (e + 16 <= end) {  // 2-deep remainder
            int i0 = csr[e + g];
            int i1 = csr[e + 8 + g];
            uint4 r0 = *reinterpret_cast<const uint4*>(g2 + ((size_t)i0 << 5) + f4 * 8);
            uint4 r1 = *reinterpret_cast<const uint4*>(g2 + ((size_t)i1 << 5) + f4 * 8);
            acc_pk_raw(r0, c2);
            acc_pk_raw(r1, c2);
            e += 16;
        }
        if (e + 8 <= end) {
            int s = csr[e + g];
            uint4 r = *reinterpret_cast<const uint4*>(g2 + ((size_t)s << 5) + f4 * 8);
            acc_pk_raw(r, c2);
            e += 8;
        }
        if (e + g < end) {
            int s = csr[e + g];
            uint4 r = *reinterpret_cast<const uint4*>(g2 + ((size_t)s << 5) + f4 * 8);
            acc_pk_raw(r, c2);
        }
        flush_pk(c2, a);
        // fold 8 edge groups within the half-wave
#pragma unroll
        for (int j = 0; j < 8; ++j) a[j] += __shfl_xor(a[j], 4);
#pragma unroll
        for (int j = 0; j < 8; ++j) a[j] += __shfl_xor(a[j], 8);
#pragma unroll
        for (int j = 0; j < 8; ++j) a[j] += __shfl_xor(a[j], 16);
    }
    __shared__ float sdata[8][32];
    if (g == 0) {  // lanes l32 0..3 hold chunks f4
        float relu[8];
        if (node < n) {
            float dn = dinv[node];
#pragma unroll
            for (int j = 0; j < 8; ++j)
                relu[j] = fmaxf(a[j] * dn + b2[f4 * 8 + j], 0.f);
        } else {
#pragma unroll
            for (int j = 0; j < 8; ++j) relu[j] = 0.f;
        }
#pragma unroll
        for (int j = 0; j < 8; ++j) sdata[half][f4 * 8 + j] = relu[j];
    }
    __syncthreads();
    if (tid < 32) {
        float s = 0.f;
#pragma unroll
        for (int r = 0; r < 8; ++r) s += sdata[r][tid];
        partials[tid * nblocks + blockIdx.x] = s;
    }
}

// 32 blocks, one per feature; fused FC: atomicAdd into pre-zeroed out[0].
__global__ __launch_bounds__(256) void reduce_fc_kernel(const float* __restrict__ partials,
                                                        int nblocks,
                                                        const float* __restrict__ fcw,
                                                        const float* __restrict__ fcb,
                                                        float* __restrict__ out, int n) {
    int f = blockIdx.x;
    const float* col = partials + (size_t)f * nblocks;
    float s = 0.f;
    for (int i = threadIdx.x; i < nblocks; i += 256) s += col[i];
    __shared__ float red[256];
    red[threadIdx.x] = s;
    __syncthreads();
    for (int ofs = 128; ofs > 0; ofs >>= 1) {
        if (threadIdx.x < ofs) red[threadIdx.x] += red[threadIdx.x + ofs];
        __syncthreads();
    }
    if (threadIdx.x == 0) {
        float v = (float)((double)red[0] / (double)n * (double)fcw[f]);
        if (f == 0) v += fcb[0];
        atomicAdd(out, v);
    }
}

// ---------------- launch ----------------

extern "C" void kernel_launch(void* const* d_in, const int* in_sizes, int n_in,
                              void* d_out, int out_size, void* d_ws, size_t ws_size,
                              hipStream_t stream) {
    const float* x   = (const float*)d_in[0];
    const int*   ei  = (const int*)d_in[1];
    const float* W1  = (const float*)d_in[2];
    const float* b1  = (const float*)d_in[3];
    const float* W2  = (const float*)d_in[4];
    const float* b2  = (const float*)d_in[5];
    const float* fcw = (const float*)d_in[6];
    const float* fcb = (const float*)d_in[7];
    float* out = (float*)d_out;

    const int N = in_sizes[0] / 256;  // 100000
    const int E = in_sizes[1] / 2;    // 3200000
    const int* src = ei;
    const int* dst = ei + E;

    const int NB = (N + BNODES - 1) >> BSH;            // 782 buckets
    const int SC = NB * NBLK;                          // hist entries
    const int CH = (((E + NBLK - 1) / NBLK) + 3) & ~3; // edges/block, x4 aligned
    const int nb2 = (N + 7) / 8;                       // agg2 blocks (8 nodes)

    char* ws = (char*)d_ws;
    size_t off = 0;
    auto alloc = [&](size_t bytes) -> void* {
        void* p = ws + off;
        off = (off + bytes + 255) & ~(size_t)255;
        return p;
    };
    int*   tmp      = (int*)alloc((size_t)SC * 4);   // scan1 (bucket offsets)
    int*   bsums    = (int*)alloc(2048);
    int*   bscan    = (int*)alloc(2048);
    int*   row_off  = (int*)alloc((size_t)N * 4);
    int*   deg      = (int*)alloc((size_t)N * 4);
    float* dinv     = (float*)alloc((size_t)N * 4);
    int*   csr      = (int*)alloc((size_t)E * 4);
    __half* W1t     = (__half*)alloc((size_t)64 * 256 * 2);
    __half* W2t     = (__half*)alloc((size_t)32 * 64 * 2);
    // region P: buck (E int) aliases g1 (N*F1 halves) — buck dead before gemm1
    size_t szP = (size_t)E * 4;
    size_t szG1 = (size_t)N * F1 * 2;
    void* P = alloc(szP > szG1 ? szP : szG1);
    int*    buck = (int*)P;
    __half* g1   = (__half*)P;
    int*   hist_T   = (int*)alloc((size_t)SC * 4);
    __half* h1      = (__half*)alloc((size_t)N * F1 * 2);
    __half* g2      = (__half*)alloc((size_t)N * F2 * 2);
    float* partials = (float*)alloc((size_t)F2 * nb2 * 4);

    // ---- CSR build via counting sort + weight prep (also zeroes out[0]) ----
    bucket_hist_prep_kernel<<<NBLK + 1, 256, 0, stream>>>(dst, hist_T, W1, W2, W1t, W2t, out, E, CH, NB);
    int nbS = (SC + 1023) / 1024;  // 391
    scan_blocks_kernel<<<nbS, 256, 0, stream>>>(hist_T, tmp, bsums, SC);
    scan_sums_kernel<<<1, 512, 0, stream>>>(bsums, bscan, nbS);
    bucket_scatter_kernel<<<NBLK, 256, 0, stream>>>(src, dst, tmp, bscan, buck, E, CH, NB);
    bucket_deg_fill_kernel<<<NB, 256, 0, stream>>>(buck, tmp, bscan, deg, dinv, row_off, csr, E, N, NB);

    int nbG = (N + 63) / 64;  // 1563
    // ---- layer 1 ----
    gemm_mfma_kernel<true, 256, 64><<<nbG, 256, 0, stream>>>(x, W1t, dinv, g1, N);
    agg1_kernel<<<(N + 3) / 4, 256, 0, stream>>>(g1, row_off, deg, csr, dinv, b1, h1, N);

    // ---- layer 2 ----
    gemm_mfma_kernel<false, 64, 32><<<nbG, 256, 0, stream>>>(h1, W2t, dinv, g2, N);
    agg2_pool_kernel<<<nb2, 256, 0, stream>>>(g2, row_off, deg, csr, dinv, b2, partials, nb2, N);

    reduce_fc_kernel<<<F2, 256, 0, stream>>>(partials, nb2, fcw, fcb, out, N);
}